// Round 2
// baseline (636.354 us; speedup 1.0000x reference)
//
#include <hip/hip_runtime.h>
#include <math.h>

// Problem constants
#define NB   2
#define VL   2048
#define TL   448
#define KL   64
#define TOT  2560     // VL+TL+KL
#define MIDL 2496     // VL+TL
#define HDIM 1024
#define NHEAD 16
#define DHEAD 64

typedef __bf16 bf16x8 __attribute__((ext_vector_type(8)));
typedef float  f32x4  __attribute__((ext_vector_type(4)));
typedef unsigned short us8 __attribute__((ext_vector_type(8)));
typedef float  fl4    __attribute__((ext_vector_type(4)));

__device__ __forceinline__ unsigned short f2bf(float f) {
    unsigned int u = __builtin_bit_cast(unsigned int, f);
    u += 0x7FFFu + ((u >> 16) & 1u);           // RNE
    return (unsigned short)(u >> 16);
}
__device__ __forceinline__ float bf2f(unsigned short u) {
    unsigned int x = ((unsigned int)u) << 16;
    return __builtin_bit_cast(float, x);
}
__device__ __forceinline__ f32x4 mfma_bf16(bf16x8 a, bf16x8 b, f32x4 c) {
    return __builtin_amdgcn_mfma_f32_16x16x32_bf16(a, b, c, 0, 0, 0);
}
__device__ __forceinline__ bf16x8 ldb(const unsigned short* p) {
    return __builtin_bit_cast(bf16x8, *(const us8*)p);
}

// ---------------------------------------------------------------- casts
// Gather-concat [vision|text|task] per batch -> X bf16 [NB*TOT][HDIM]
__global__ __launch_bounds__(256) void k_cast_hs(
    const float* __restrict__ vis, const float* __restrict__ txt,
    const float* __restrict__ tsk, unsigned short* __restrict__ X)
{
    size_t idx = ((size_t)blockIdx.x * 256 + threadIdx.x) * 4;
    if (idx >= (size_t)NB * TOT * HDIM) return;
    size_t r = idx >> 10; int c = (int)(idx & 1023);
    int b = (int)(r / TOT), s = (int)(r % TOT);
    const float* src;
    if (s < VL)        src = vis + ((size_t)b * VL + s) * HDIM;
    else if (s < MIDL) src = txt + ((size_t)b * TL + (s - VL)) * HDIM;
    else               src = tsk + ((size_t)b * KL + (s - MIDL)) * HDIM;
    fl4 v = *(const fl4*)(src + c);
    X[idx + 0] = f2bf(v[0]); X[idx + 1] = f2bf(v[1]);
    X[idx + 2] = f2bf(v[2]); X[idx + 3] = f2bf(v[3]);
}

__global__ __launch_bounds__(256) void k_cast(
    const float* __restrict__ in, unsigned short* __restrict__ out, int n)
{
    int idx = (blockIdx.x * 256 + threadIdx.x) * 4;
    if (idx >= n) return;
    fl4 v = *(const fl4*)(in + idx);
    out[idx + 0] = f2bf(v[0]); out[idx + 1] = f2bf(v[1]);
    out[idx + 2] = f2bf(v[2]); out[idx + 3] = f2bf(v[3]);
}

// ---------------------------------------------------------------- GEMM
// C[M][N] = A[M][K](bf16) * W[N][K]^T(bf16) + bias[N]; 128x128 tile, BK=32,
// 4 waves in 2x2, each wave 64x64 via 4x4 16x16x32 MFMA frags.
// Staging: 256 threads x 16 elems = 4096 = full 128x32 tile (R1 fix: was 8/thread).
template<bool BF16OUT>
__global__ __launch_bounds__(256) void k_gemm_bt(
    const unsigned short* __restrict__ A, const unsigned short* __restrict__ W,
    const float* __restrict__ bias, void* __restrict__ Cv,
    int M, int N, int K)
{
    __shared__ unsigned short As[128][40];   // +8 pad
    __shared__ unsigned short Bs[128][40];
    const int row0 = blockIdx.x * 128, col0 = blockIdx.y * 128;
    const int t = threadIdx.x;
    const int lane = t & 63, wave = t >> 6;
    const int wr = wave >> 1, wc = wave & 1;
    const int lrow = lane & 15, lgrp = lane >> 4;

    f32x4 acc[4][4];
    #pragma unroll
    for (int m = 0; m < 4; ++m)
        #pragma unroll
        for (int n = 0; n < 4; ++n)
            acc[m][n] = (f32x4){0.f, 0.f, 0.f, 0.f};

    const int r = t >> 1, hc = (t & 1) * 16;
    const unsigned short* Ap = A + (size_t)(row0 + r) * K + hc;
    const unsigned short* Wp = W + (size_t)(col0 + r) * K + hc;

    for (int kk = 0; kk < K; kk += 32) {
        us8 a0 = *(const us8*)(Ap + kk);
        us8 a1 = *(const us8*)(Ap + kk + 8);
        us8 b0 = *(const us8*)(Wp + kk);
        us8 b1 = *(const us8*)(Wp + kk + 8);
        __syncthreads();                       // protect prior frag reads
        *(us8*)&As[r][hc]     = a0;
        *(us8*)&As[r][hc + 8] = a1;
        *(us8*)&Bs[r][hc]     = b0;
        *(us8*)&Bs[r][hc + 8] = b1;
        __syncthreads();
        bf16x8 af[4], bfr[4];
        #pragma unroll
        for (int m = 0; m < 4; ++m) af[m]  = ldb(&As[wr*64 + m*16 + lrow][lgrp*8]);
        #pragma unroll
        for (int n = 0; n < 4; ++n) bfr[n] = ldb(&Bs[wc*64 + n*16 + lrow][lgrp*8]);
        #pragma unroll
        for (int m = 0; m < 4; ++m)
            #pragma unroll
            for (int n = 0; n < 4; ++n)
                acc[m][n] = mfma_bf16(af[m], bfr[n], acc[m][n]);
    }
    #pragma unroll
    for (int m = 0; m < 4; ++m) {
        #pragma unroll
        for (int n = 0; n < 4; ++n) {
            int col = col0 + wc*64 + n*16 + lrow;
            float bs = bias[col];
            #pragma unroll
            for (int q = 0; q < 4; ++q) {
                int row = row0 + wr*64 + m*16 + lgrp*4 + q;   // verified C layout
                float v = acc[m][n][q] + bs;
                if (BF16OUT) ((unsigned short*)Cv)[(size_t)row * N + col] = f2bf(v);
                else         ((float*)Cv)[(size_t)row * N + col] = v;
            }
        }
    }
}

// ---------------------------------------------------------------- attention
// Flash-style. Grid (Lq/64, NHEAD, NB). 4 waves x 16 q-rows. scale = 1/64.
__global__ __launch_bounds__(256) void k_attn(
    const unsigned short* __restrict__ Qb, const unsigned short* __restrict__ Kb,
    const unsigned short* __restrict__ Vb, unsigned short* __restrict__ Ob,
    int Lk, size_t q_bs, size_t k_bs, size_t o_bs, float scale)
{
    __shared__ unsigned short Qs[64][72];
    __shared__ unsigned short Ks[64][72];
    __shared__ unsigned short Vt[64][72];      // V transposed: [d][key]
    __shared__ unsigned short Ps[4][16][72];   // per-wave P re-layout

    const int b = blockIdx.z, h = blockIdx.y, qb = blockIdx.x;
    const unsigned short* Q = Qb + (size_t)b * q_bs + h * 64;
    const unsigned short* K = Kb + (size_t)b * k_bs + h * 64;
    const unsigned short* V = Vb + (size_t)b * k_bs + h * 64;
    unsigned short*       O = Ob + (size_t)b * o_bs + h * 64;
    const int t = threadIdx.x;
    const int wave = t >> 6, lane = t & 63;
    const int lrow = lane & 15, lgrp = lane >> 4;
    const int q0r = qb * 64;

    #pragma unroll
    for (int i = 0; i < 2; ++i) {              // stage Q tile [64][64]
        int c = t + i * 256, rr = c >> 3, off = (c & 7) * 8;
        *(us8*)&Qs[rr][off] = *(const us8*)(Q + (size_t)(q0r + rr) * HDIM + off);
    }
    __syncthreads();
    bf16x8 qf0 = ldb(&Qs[wave*16 + lrow][lgrp*8]);
    bf16x8 qf1 = ldb(&Qs[wave*16 + lrow][32 + lgrp*8]);

    f32x4 oacc[4];
    #pragma unroll
    for (int d = 0; d < 4; ++d) oacc[d] = (f32x4){0.f, 0.f, 0.f, 0.f};
    float mr[4] = {-INFINITY, -INFINITY, -INFINITY, -INFINITY};
    float lsum[4] = {0.f, 0.f, 0.f, 0.f};

    const int nkt = Lk >> 6;
    for (int kt = 0; kt < nkt; ++kt) {
        us8 kreg[2], vreg[2];
        #pragma unroll
        for (int i = 0; i < 2; ++i) {
            int c = t + i * 256, rr = c >> 3, off = (c & 7) * 8;
            kreg[i] = *(const us8*)(K + (size_t)(kt*64 + rr) * HDIM + off);
            vreg[i] = *(const us8*)(V + (size_t)(kt*64 + rr) * HDIM + off);
        }
        __syncthreads();                       // prior tile's reads done
        #pragma unroll
        for (int i = 0; i < 2; ++i) {
            int c = t + i * 256, rr = c >> 3, off = (c & 7) * 8;
            *(us8*)&Ks[rr][off] = kreg[i];
            #pragma unroll
            for (int j = 0; j < 8; ++j) Vt[off + j][rr] = vreg[i][j];
        }
        __syncthreads();

        // S = Q K^T  (rows=q, cols=key)
        f32x4 s[4];
        #pragma unroll
        for (int nf = 0; nf < 4; ++nf) {
            bf16x8 kf0 = ldb(&Ks[nf*16 + lrow][lgrp*8]);
            bf16x8 kf1 = ldb(&Ks[nf*16 + lrow][32 + lgrp*8]);
            f32x4 z = (f32x4){0.f, 0.f, 0.f, 0.f};
            z = mfma_bf16(qf0, kf0, z);
            z = mfma_bf16(qf1, kf1, z);
            s[nf] = z * scale;
        }
        // online softmax; row = lgrp*4+q lives in 16 lanes (same lgrp)
        float mt[4];
        #pragma unroll
        for (int q = 0; q < 4; ++q)
            mt[q] = fmaxf(fmaxf(s[0][q], s[1][q]), fmaxf(s[2][q], s[3][q]));
        #pragma unroll
        for (int m = 1; m < 16; m <<= 1)
            #pragma unroll
            for (int q = 0; q < 4; ++q)
                mt[q] = fmaxf(mt[q], __shfl_xor(mt[q], m, 64));
        float al[4], rs[4];
        #pragma unroll
        for (int q = 0; q < 4; ++q) {
            float mn = fmaxf(mr[q], mt[q]);
            al[q] = __expf(mr[q] - mn);
            mr[q] = mn;
            rs[q] = 0.f;
        }
        #pragma unroll
        for (int nf = 0; nf < 4; ++nf)
            #pragma unroll
            for (int q = 0; q < 4; ++q) {
                float p = __expf(s[nf][q] - mr[q]);
                unsigned short pu = f2bf(p);
                Ps[wave][lgrp*4 + q][nf*16 + lrow] = pu;
                rs[q] += bf2f(pu);             // sum the quantized P
            }
        #pragma unroll
        for (int m = 1; m < 16; m <<= 1)
            #pragma unroll
            for (int q = 0; q < 4; ++q)
                rs[q] += __shfl_xor(rs[q], m, 64);
        #pragma unroll
        for (int q = 0; q < 4; ++q) lsum[q] = lsum[q] * al[q] + rs[q];
        #pragma unroll
        for (int d = 0; d < 4; ++d)
            #pragma unroll
            for (int q = 0; q < 4; ++q) oacc[d][q] *= al[q];

        // PV: A = P (from per-wave LDS), B = Vt
        bf16x8 pf0 = ldb(&Ps[wave][lrow][lgrp*8]);
        bf16x8 pf1 = ldb(&Ps[wave][lrow][32 + lgrp*8]);
        #pragma unroll
        for (int df = 0; df < 4; ++df) {
            bf16x8 v0 = ldb(&Vt[df*16 + lrow][lgrp*8]);
            bf16x8 v1 = ldb(&Vt[df*16 + lrow][32 + lgrp*8]);
            oacc[df] = mfma_bf16(pf0, v0, oacc[df]);
            oacc[df] = mfma_bf16(pf1, v1, oacc[df]);
        }
    }
    #pragma unroll
    for (int df = 0; df < 4; ++df)
        #pragma unroll
        for (int q = 0; q < 4; ++q) {
            float v = oacc[df][q] / lsum[q];
            int row = q0r + wave*16 + lgrp*4 + q;
            O[(size_t)row * HDIM + df*16 + lrow] = f2bf(v);
        }
}

// ---------------------------------------------------------------- mid linear
// q1/k1/v1[rows 64..2559] = mid @ w1^T + b1 per head (K=64). Grid (39, 16).
// Writes IN-PLACE into q0/k0/v0 buffers (they are dead after stage-1 attn).
__global__ __launch_bounds__(256) void k_midlin(
    const unsigned short* __restrict__ mid,
    const unsigned short* __restrict__ wq, const unsigned short* __restrict__ wk,
    const unsigned short* __restrict__ wv,
    const float* __restrict__ bq, const float* __restrict__ bk,
    const float* __restrict__ bv,
    unsigned short* __restrict__ q1, unsigned short* __restrict__ k1,
    unsigned short* __restrict__ v1)
{
    __shared__ unsigned short As[128][72];
    const int r0 = blockIdx.x * 128, h = blockIdx.y;
    const int t = threadIdx.x;
    const int wave = t >> 6, lane = t & 63;
    const int lrow = lane & 15, lgrp = lane >> 4;

    #pragma unroll
    for (int i = 0; i < 4; ++i) {
        int c = t + i * 256, rr = c >> 3, off = (c & 7) * 8;
        *(us8*)&As[rr][off] = *(const us8*)(mid + (size_t)(r0 + rr) * HDIM + h*64 + off);
    }
    __syncthreads();
    bf16x8 af[2][2];
    #pragma unroll
    for (int m = 0; m < 2; ++m)
        #pragma unroll
        for (int kf = 0; kf < 2; ++kf)
            af[m][kf] = ldb(&As[wave*32 + m*16 + lrow][kf*32 + lgrp*8]);

    const unsigned short* ws[3] = {wq, wk, wv};
    const float* bs[3] = {bq, bk, bv};
    unsigned short* ds[3] = {q1, k1, v1};
    for (int o = 0; o < 3; ++o) {
        bf16x8 bfr[4][2];
        #pragma unroll
        for (int n = 0; n < 4; ++n)
            #pragma unroll
            for (int kf = 0; kf < 2; ++kf)
                bfr[n][kf] = __builtin_bit_cast(bf16x8,
                    *(const us8*)(ws[o] + (size_t)(n*16 + lrow) * 64 + kf*32 + lgrp*8));
        f32x4 acc[2][4];
        #pragma unroll
        for (int m = 0; m < 2; ++m)
            #pragma unroll
            for (int n = 0; n < 4; ++n) {
                f32x4 z = (f32x4){0.f, 0.f, 0.f, 0.f};
                z = mfma_bf16(af[m][0], bfr[n][0], z);
                z = mfma_bf16(af[m][1], bfr[n][1], z);
                acc[m][n] = z;
            }
        #pragma unroll
        for (int m = 0; m < 2; ++m)
            #pragma unroll
            for (int n = 0; n < 4; ++n) {
                float bb = bs[o][n*16 + lrow];
                #pragma unroll
                for (int q = 0; q < 4; ++q) {
                    int gr = r0 + wave*32 + m*16 + lgrp*4 + q;   // 0..4991
                    int bi = gr / MIDL, seq = gr % MIDL;
                    size_t drow = (size_t)bi * TOT + 64 + seq;   // after task block
                    ds[o][drow * HDIM + h*64 + n*16 + lrow] = f2bf(acc[m][n][q] + bb);
                }
            }
    }
}

// Task rows -> rows [0,64) of the q1/k1/v1 buffers (in-place in q0/k0/v0).
// q1<-q0.task, k1<-k0.task, v1<-q0.task (reference quirk: kv = q0 slice).
// Reads rows [2496,2560), writes rows [0,64): disjoint. MUST run before midlin.
__global__ __launch_bounds__(256) void k_copy_task(
    const unsigned short* __restrict__ q0, const unsigned short* __restrict__ k0,
    unsigned short* __restrict__ q1, unsigned short* __restrict__ k1,
    unsigned short* __restrict__ v1)
{
    int blk = blockIdx.x;                 // [tensor(3)][b(2)][row(64)]
    int tensor = blk >> 7, rem = blk & 127;
    int b = rem >> 6, rr = rem & 63;
    const unsigned short* src = (tensor == 1) ? k0 : q0;
    unsigned short* dst = (tensor == 0) ? q1 : (tensor == 1 ? k1 : v1);
    size_t srow = (size_t)b * TOT + MIDL + rr;
    size_t drow = (size_t)b * TOT + rr;
    int t = threadIdx.x;
    if (t < 128)
        ((us8*)(dst + drow * HDIM))[t] = ((const us8*)(src + srow * HDIM))[t];
}

// ---------------------------------------------------------------- launcher
extern "C" void kernel_launch(void* const* d_in, const int* in_sizes, int n_in,
                              void* d_out, int out_size, void* d_ws, size_t ws_size,
                              hipStream_t stream)
{
    (void)in_sizes; (void)n_in; (void)out_size; (void)ws_size;
    const float* vis = (const float*)d_in[0];
    const float* txt = (const float*)d_in[1];
    const float* tsk = (const float*)d_in[2];
    const float* wq0 = (const float*)d_in[3];
    const float* bq0 = (const float*)d_in[4];
    const float* wk0 = (const float*)d_in[5];
    const float* bk0 = (const float*)d_in[6];
    const float* wv0 = (const float*)d_in[7];
    const float* bv0 = (const float*)d_in[8];
    const float* wq1 = (const float*)d_in[9];
    const float* bq1 = (const float*)d_in[10];
    const float* wk1 = (const float*)d_in[11];
    const float* bk1 = (const float*)d_in[12];
    const float* wv1 = (const float*)d_in[13];
    const float* bv1 = (const float*)d_in[14];
    const float* wo  = (const float*)d_in[15];
    const float* bo  = (const float*)d_in[16];

    char* ws = (char*)d_ws;
    size_t off = 0;
    auto carve = [&](size_t bytes) -> char* {
        char* p = ws + off;
        off += (bytes + 255) & ~(size_t)255;
        return p;
    };
    const size_t ELX = (size_t)NB * TOT * HDIM;           // 5,242,880
    // Buffer plan (~50 MB total), lifetime-aliased:
    //   X: hs -> (dead after QKV GEMMs) -> mid -> (dead after midlin) -> out2
    //   q0/k0/v0: stage-1 QKV -> (attn1 done) -> q1/k1/v1 written in place
    unsigned short* X    = (unsigned short*)carve(ELX * 2);
    unsigned short* q0   = (unsigned short*)carve(ELX * 2);
    unsigned short* k0   = (unsigned short*)carve(ELX * 2);
    unsigned short* v0   = (unsigned short*)carve(ELX * 2);
    unsigned short* wq0b = (unsigned short*)carve((size_t)HDIM * HDIM * 2);
    unsigned short* wk0b = (unsigned short*)carve((size_t)HDIM * HDIM * 2);
    unsigned short* wv0b = (unsigned short*)carve((size_t)HDIM * HDIM * 2);
    unsigned short* wob  = (unsigned short*)carve((size_t)HDIM * HDIM * 2);
    unsigned short* wq1b = (unsigned short*)carve(64 * 64 * 2);
    unsigned short* wk1b = (unsigned short*)carve(64 * 64 * 2);
    unsigned short* wv1b = (unsigned short*)carve(64 * 64 * 2);
    unsigned short* mid  = X;     // NB*MIDL*HDIM elems, fits in X
    unsigned short* q1   = q0;
    unsigned short* k1   = k0;
    unsigned short* v1   = v0;
    unsigned short* out2 = X;     // mid dead after midlin

    const float scale = 1.0f / 64.0f;   // reference divides by d, not sqrt(d)

    k_cast_hs<<<5120, 256, 0, stream>>>(vis, txt, tsk, X);
    k_cast<<<1024, 256, 0, stream>>>(wq0, wq0b, HDIM * HDIM);
    k_cast<<<1024, 256, 0, stream>>>(wk0, wk0b, HDIM * HDIM);
    k_cast<<<1024, 256, 0, stream>>>(wv0, wv0b, HDIM * HDIM);
    k_cast<<<1024, 256, 0, stream>>>(wo,  wob,  HDIM * HDIM);
    k_cast<<<4, 256, 0, stream>>>(wq1, wq1b, 64 * 64);
    k_cast<<<4, 256, 0, stream>>>(wk1, wk1b, 64 * 64);
    k_cast<<<4, 256, 0, stream>>>(wv1, wv1b, 64 * 64);

    dim3 g1(40, 8);
    k_gemm_bt<true><<<g1, 256, 0, stream>>>(X, wq0b, bq0, q0, NB*TOT, HDIM, HDIM);
    k_gemm_bt<true><<<g1, 256, 0, stream>>>(X, wk0b, bk0, k0, NB*TOT, HDIM, HDIM);
    k_gemm_bt<true><<<g1, 256, 0, stream>>>(X, wv0b, bv0, v0, NB*TOT, HDIM, HDIM);

    // v2t: Q=vision rows of q0, K/V=text rows of k0/v0 -> mid rows [0,2048)
    k_attn<<<dim3(VL/64, NHEAD, NB), 256, 0, stream>>>(
        q0, k0 + (size_t)VL * HDIM, v0 + (size_t)VL * HDIM, mid,
        TL, (size_t)TOT * HDIM, (size_t)TOT * HDIM, (size_t)MIDL * HDIM, scale);
    // t2v: Q=text rows, K/V=vision rows -> mid rows [2048,2496)
    k_attn<<<dim3(TL/64, NHEAD, NB), 256, 0, stream>>>(
        q0 + (size_t)VL * HDIM, k0, v0, mid + (size_t)VL * HDIM,
        VL, (size_t)TOT * HDIM, (size_t)TOT * HDIM, (size_t)MIDL * HDIM, scale);

    // Task rows first (reads q0/k0 task rows before midlin overwrites them)
    k_copy_task<<<384, 256, 0, stream>>>(q0, k0, q1, k1, v1);
    k_midlin<<<dim3(39, NHEAD), 256, 0, stream>>>(
        mid, wq1b, wk1b, wv1b, bq1, bk1, bv1, q1, k1, v1);

    // stage-2 attention over [task, v2t, t2v] ordering
    k_attn<<<dim3(TOT/64, NHEAD, NB), 256, 0, stream>>>(
        q1, k1, v1, out2,
        TOT, (size_t)TOT * HDIM, (size_t)TOT * HDIM, (size_t)TOT * HDIM, scale);

    k_gemm_bt<false><<<g1, 256, 0, stream>>>(out2, wob, bo, (float*)d_out,
                                             NB*TOT, HDIM, HDIM);
}

// Round 4
// 506.371 us; speedup vs baseline: 1.2567x; 1.2567x over previous
//
#include <hip/hip_runtime.h>
#include <math.h>

// Problem constants
#define NB   2
#define VL   2048
#define TL   448
#define KL   64
#define TOT  2560     // VL+TL+KL
#define MIDL 2496     // VL+TL
#define HDIM 1024
#define NHEAD 16
#define DHEAD 64

typedef __bf16 bf16x8 __attribute__((ext_vector_type(8)));
typedef float  f32x4  __attribute__((ext_vector_type(4)));
typedef unsigned short us8 __attribute__((ext_vector_type(8)));
typedef float  fl4    __attribute__((ext_vector_type(4)));

__device__ __forceinline__ unsigned short f2bf(float f) {
    unsigned int u = __builtin_bit_cast(unsigned int, f);
    u += 0x7FFFu + ((u >> 16) & 1u);           // RNE
    return (unsigned short)(u >> 16);
}
__device__ __forceinline__ float bf2f(unsigned short u) {
    unsigned int x = ((unsigned int)u) << 16;
    return __builtin_bit_cast(float, x);
}
__device__ __forceinline__ f32x4 mfma_bf16(bf16x8 a, bf16x8 b, f32x4 c) {
    return __builtin_amdgcn_mfma_f32_16x16x32_bf16(a, b, c, 0, 0, 0);
}
__device__ __forceinline__ bf16x8 ldb(const unsigned short* p) {
    return __builtin_bit_cast(bf16x8, *(const us8*)p);
}

// ---------------------------------------------------------------- casts
__global__ __launch_bounds__(256) void k_cast_hs(
    const float* __restrict__ vis, const float* __restrict__ txt,
    const float* __restrict__ tsk, unsigned short* __restrict__ X)
{
    size_t idx = ((size_t)blockIdx.x * 256 + threadIdx.x) * 4;
    if (idx >= (size_t)NB * TOT * HDIM) return;
    size_t r = idx >> 10; int c = (int)(idx & 1023);
    int b = (int)(r / TOT), s = (int)(r % TOT);
    const float* src;
    if (s < VL)        src = vis + ((size_t)b * VL + s) * HDIM;
    else if (s < MIDL) src = txt + ((size_t)b * TL + (s - VL)) * HDIM;
    else               src = tsk + ((size_t)b * KL + (s - MIDL)) * HDIM;
    fl4 v = *(const fl4*)(src + c);
    X[idx + 0] = f2bf(v[0]); X[idx + 1] = f2bf(v[1]);
    X[idx + 2] = f2bf(v[2]); X[idx + 3] = f2bf(v[3]);
}

__global__ __launch_bounds__(256) void k_cast(
    const float* __restrict__ in, unsigned short* __restrict__ out, int n)
{
    int idx = (blockIdx.x * 256 + threadIdx.x) * 4;
    if (idx >= n) return;
    fl4 v = *(const fl4*)(in + idx);
    out[idx + 0] = f2bf(v[0]); out[idx + 1] = f2bf(v[1]);
    out[idx + 2] = f2bf(v[2]); out[idx + 3] = f2bf(v[3]);
}

// ---------------------------------------------------------------- GEMM (out-proj)
template<bool BF16OUT>
__global__ __launch_bounds__(256) void k_gemm_bt(
    const unsigned short* __restrict__ A, const unsigned short* __restrict__ W,
    const float* __restrict__ bias, void* __restrict__ Cv,
    int M, int N, int K)
{
    __shared__ unsigned short As[128][40];
    __shared__ unsigned short Bs[128][40];
    const int row0 = blockIdx.x * 128, col0 = blockIdx.y * 128;
    const int t = threadIdx.x;
    const int lane = t & 63, wave = t >> 6;
    const int wr = wave >> 1, wc = wave & 1;
    const int lrow = lane & 15, lgrp = lane >> 4;

    f32x4 acc[4][4];
    #pragma unroll
    for (int m = 0; m < 4; ++m)
        #pragma unroll
        for (int n = 0; n < 4; ++n)
            acc[m][n] = (f32x4){0.f, 0.f, 0.f, 0.f};

    const int r = t >> 1, hc = (t & 1) * 16;
    const unsigned short* Ap = A + (size_t)(row0 + r) * K + hc;
    const unsigned short* Wp = W + (size_t)(col0 + r) * K + hc;

    for (int kk = 0; kk < K; kk += 32) {
        us8 a0 = *(const us8*)(Ap + kk);
        us8 a1 = *(const us8*)(Ap + kk + 8);
        us8 b0 = *(const us8*)(Wp + kk);
        us8 b1 = *(const us8*)(Wp + kk + 8);
        __syncthreads();
        *(us8*)&As[r][hc]     = a0;
        *(us8*)&As[r][hc + 8] = a1;
        *(us8*)&Bs[r][hc]     = b0;
        *(us8*)&Bs[r][hc + 8] = b1;
        __syncthreads();
        bf16x8 af[4], bfr[4];
        #pragma unroll
        for (int m = 0; m < 4; ++m) af[m]  = ldb(&As[wr*64 + m*16 + lrow][lgrp*8]);
        #pragma unroll
        for (int n = 0; n < 4; ++n) bfr[n] = ldb(&Bs[wc*64 + n*16 + lrow][lgrp*8]);
        #pragma unroll
        for (int m = 0; m < 4; ++m)
            #pragma unroll
            for (int n = 0; n < 4; ++n)
                acc[m][n] = mfma_bf16(af[m], bfr[n], acc[m][n]);
    }
    #pragma unroll
    for (int m = 0; m < 4; ++m) {
        #pragma unroll
        for (int n = 0; n < 4; ++n) {
            int col = col0 + wc*64 + n*16 + lrow;
            float bs = bias[col];
            #pragma unroll
            for (int q = 0; q < 4; ++q) {
                int row = row0 + wr*64 + m*16 + lgrp*4 + q;
                float v = acc[m][n][q] + bs;
                if (BF16OUT) ((unsigned short*)Cv)[(size_t)row * N + col] = f2bf(v);
                else         ((float*)Cv)[(size_t)row * N + col] = v;
            }
        }
    }
}

// Fused QKV: M=5120, N=3072 (planes q|k|v), K=1024. W rows contiguous.
__global__ __launch_bounds__(256) void k_gemm_qkv(
    const unsigned short* __restrict__ A, const unsigned short* __restrict__ W,
    const float* __restrict__ b0, const float* __restrict__ b1,
    const float* __restrict__ b2,
    unsigned short* __restrict__ C0, unsigned short* __restrict__ C1,
    unsigned short* __restrict__ C2)
{
    __shared__ unsigned short As[128][40];
    __shared__ unsigned short Bs[128][40];
    const int row0 = blockIdx.x * 128, col0 = blockIdx.y * 128;
    const int t = threadIdx.x;
    const int lane = t & 63, wave = t >> 6;
    const int wr = wave >> 1, wc = wave & 1;
    const int lrow = lane & 15, lgrp = lane >> 4;

    f32x4 acc[4][4];
    #pragma unroll
    for (int m = 0; m < 4; ++m)
        #pragma unroll
        for (int n = 0; n < 4; ++n)
            acc[m][n] = (f32x4){0.f, 0.f, 0.f, 0.f};

    const int r = t >> 1, hc = (t & 1) * 16;
    const unsigned short* Ap = A + (size_t)(row0 + r) * HDIM + hc;
    const unsigned short* Wp = W + (size_t)(col0 + r) * HDIM + hc;

    for (int kk = 0; kk < HDIM; kk += 32) {
        us8 a0 = *(const us8*)(Ap + kk);
        us8 a1 = *(const us8*)(Ap + kk + 8);
        us8 b0v = *(const us8*)(Wp + kk);
        us8 b1v = *(const us8*)(Wp + kk + 8);
        __syncthreads();
        *(us8*)&As[r][hc]     = a0;
        *(us8*)&As[r][hc + 8] = a1;
        *(us8*)&Bs[r][hc]     = b0v;
        *(us8*)&Bs[r][hc + 8] = b1v;
        __syncthreads();
        bf16x8 af[4], bfr[4];
        #pragma unroll
        for (int m = 0; m < 4; ++m) af[m]  = ldb(&As[wr*64 + m*16 + lrow][lgrp*8]);
        #pragma unroll
        for (int n = 0; n < 4; ++n) bfr[n] = ldb(&Bs[wc*64 + n*16 + lrow][lgrp*8]);
        #pragma unroll
        for (int m = 0; m < 4; ++m)
            #pragma unroll
            for (int n = 0; n < 4; ++n)
                acc[m][n] = mfma_bf16(af[m], bfr[n], acc[m][n]);
    }
    const int plane = col0 >> 10;
    const float* bp = (plane == 0) ? b0 : (plane == 1) ? b1 : b2;
    unsigned short* Cp = (plane == 0) ? C0 : (plane == 1) ? C1 : C2;
    const int cl0 = col0 & 1023;
    #pragma unroll
    for (int m = 0; m < 4; ++m) {
        #pragma unroll
        for (int n = 0; n < 4; ++n) {
            int col = cl0 + wc*64 + n*16 + lrow;
            float bs = bp[col];
            #pragma unroll
            for (int q = 0; q < 4; ++q) {
                int row = row0 + wr*64 + m*16 + lgrp*4 + q;
                Cp[(size_t)row * HDIM + col] = f2bf(acc[m][n][q] + bs);
            }
        }
    }
}

// ---------------------------------------------------------------- attention
// Flash-style, grid (Lq/64, NHEAD, NB), 4 waves x 16 q-rows, scale = 1/64.
// V transposed into LDS with XOR block-swizzle: elem (k,d) stored at
// Vt[d][ ((k>>3)^(d>>3))*8 + (k&7) ], rowstride 72. Writes: per-lane constant
// column, d-octet XOR spreads 8 bank-quads -> conflict-free. Reads: one
// aligned ds_read_b128 per frag at block (lgrp^f), exact bank minimum.
// Qs and Vt share one LDS buffer (Q frags are register-resident after load).
__global__ __launch_bounds__(256) void k_attn(
    const unsigned short* __restrict__ Qb, const unsigned short* __restrict__ Kb,
    const unsigned short* __restrict__ Vb, unsigned short* __restrict__ Ob,
    int Lk, size_t q_bs, size_t k_bs, size_t o_bs, float scale)
{
    __shared__ unsigned short QV[64 * 72];     // Qs[64][72], then swizzled Vt
    __shared__ unsigned short Ks[64][72];
    __shared__ unsigned short Ps[4][16][72];

    const int b = blockIdx.z, h = blockIdx.y, qb = blockIdx.x;
    const unsigned short* Q = Qb + (size_t)b * q_bs + h * 64;
    const unsigned short* K = Kb + (size_t)b * k_bs + h * 64;
    const unsigned short* V = Vb + (size_t)b * k_bs + h * 64;
    unsigned short*       O = Ob + (size_t)b * o_bs + h * 64;
    const int t = threadIdx.x;
    const int wave = t >> 6, lane = t & 63;
    const int lrow = lane & 15, lgrp = lane >> 4;
    const int q0r = qb * 64;

    #pragma unroll
    for (int i = 0; i < 2; ++i) {              // stage Q tile [64][64]
        int c = t + i * 256, rr = c >> 3, off = (c & 7) * 8;
        *(us8*)&QV[rr*72 + off] = *(const us8*)(Q + (size_t)(q0r + rr) * HDIM + off);
    }
    __syncthreads();
    bf16x8 qf0 = ldb(&QV[(wave*16 + lrow)*72 + lgrp*8]);
    bf16x8 qf1 = ldb(&QV[(wave*16 + lrow)*72 + 32 + lgrp*8]);
    // QV is reused as Vt after the first in-loop barrier (qf reads drained).

    f32x4 oacc[4];
    #pragma unroll
    for (int d = 0; d < 4; ++d) oacc[d] = (f32x4){0.f, 0.f, 0.f, 0.f};
    float mr[4] = {-INFINITY, -INFINITY, -INFINITY, -INFINITY};
    float lsum[4] = {0.f, 0.f, 0.f, 0.f};

    const int nkt = Lk >> 6;
    for (int kt = 0; kt < nkt; ++kt) {
        us8 kreg[2], vreg[2];
        #pragma unroll
        for (int i = 0; i < 2; ++i) {
            int c = t + i * 256, rr = c >> 3, off = (c & 7) * 8;
            kreg[i] = *(const us8*)(K + (size_t)(kt*64 + rr) * HDIM + off);
            vreg[i] = *(const us8*)(V + (size_t)(kt*64 + rr) * HDIM + off);
        }
        __syncthreads();                       // prior tile reads (and qf) done
        #pragma unroll
        for (int i = 0; i < 2; ++i) {
            int c = t + i * 256, rr = c >> 3, off = (c & 7) * 8;
            *(us8*)&Ks[rr][off] = kreg[i];
            // swizzled transpose: col' constant per lane, rows off..off+7
            int colp = (((rr >> 3) ^ (off >> 3)) << 3) + (rr & 7);
            #pragma unroll
            for (int j = 0; j < 8; ++j)
                QV[(off + j)*72 + colp] = vreg[i][j];
        }
        __syncthreads();

        // S = Q K^T
        f32x4 s[4];
        #pragma unroll
        for (int nf = 0; nf < 4; ++nf) {
            bf16x8 kf0 = ldb(&Ks[nf*16 + lrow][lgrp*8]);
            bf16x8 kf1 = ldb(&Ks[nf*16 + lrow][32 + lgrp*8]);
            f32x4 z = (f32x4){0.f, 0.f, 0.f, 0.f};
            z = mfma_bf16(qf0, kf0, z);
            z = mfma_bf16(qf1, kf1, z);
            s[nf] = z * scale;
        }
        // online softmax (row = lgrp*4+q, spread over 16 lanes of same lgrp)
        float mt[4];
        #pragma unroll
        for (int q = 0; q < 4; ++q)
            mt[q] = fmaxf(fmaxf(s[0][q], s[1][q]), fmaxf(s[2][q], s[3][q]));
        #pragma unroll
        for (int m = 1; m < 16; m <<= 1)
            #pragma unroll
            for (int q = 0; q < 4; ++q)
                mt[q] = fmaxf(mt[q], __shfl_xor(mt[q], m, 64));
        float al[4], rs[4];
        #pragma unroll
        for (int q = 0; q < 4; ++q) {
            float mn = fmaxf(mr[q], mt[q]);
            al[q] = __expf(mr[q] - mn);
            mr[q] = mn;
            rs[q] = 0.f;
        }
        #pragma unroll
        for (int nf = 0; nf < 4; ++nf)
            #pragma unroll
            for (int q = 0; q < 4; ++q) {
                float p = __expf(s[nf][q] - mr[q]);
                unsigned short pu = f2bf(p);
                Ps[wave][lgrp*4 + q][nf*16 + lrow] = pu;
                rs[q] += bf2f(pu);
            }
        #pragma unroll
        for (int m = 1; m < 16; m <<= 1)
            #pragma unroll
            for (int q = 0; q < 4; ++q)
                rs[q] += __shfl_xor(rs[q], m, 64);
        #pragma unroll
        for (int q = 0; q < 4; ++q) lsum[q] = lsum[q] * al[q] + rs[q];
        #pragma unroll
        for (int d = 0; d < 4; ++d)
            #pragma unroll
            for (int q = 0; q < 4; ++q) oacc[d][q] *= al[q];

        // PV: A = P (LDS round-trip), B = swizzled Vt reads
        bf16x8 pf0 = ldb(&Ps[wave][lrow][lgrp*8]);
        bf16x8 pf1 = ldb(&Ps[wave][lrow][32 + lgrp*8]);
        #pragma unroll
        for (int df = 0; df < 4; ++df) {
            int d = df*16 + lrow;
            int f = (d >> 3) & 7;              // = 2*df + (lrow>>3)
            bf16x8 v0 = ldb(&QV[d*72 + ((lgrp ^ f) << 3)]);          // k=lgrp*8+e
            bf16x8 v1 = ldb(&QV[d*72 + (((4 | lgrp) ^ f) << 3)]);    // k=32+lgrp*8+e
            oacc[df] = mfma_bf16(pf0, v0, oacc[df]);
            oacc[df] = mfma_bf16(pf1, v1, oacc[df]);
        }
    }
    #pragma unroll
    for (int df = 0; df < 4; ++df)
        #pragma unroll
        for (int q = 0; q < 4; ++q) {
            float v = oacc[df][q] / lsum[q];
            int row = q0r + wave*16 + lgrp*4 + q;
            O[(size_t)row * HDIM + df*16 + lrow] = f2bf(v);
        }
}

// ---------------------------------------------------------------- mid linear
__global__ __launch_bounds__(256) void k_midlin(
    const unsigned short* __restrict__ mid,
    const unsigned short* __restrict__ wq, const unsigned short* __restrict__ wk,
    const unsigned short* __restrict__ wv,
    const float* __restrict__ bq, const float* __restrict__ bk,
    const float* __restrict__ bv,
    unsigned short* __restrict__ q1, unsigned short* __restrict__ k1,
    unsigned short* __restrict__ v1)
{
    __shared__ unsigned short As[128][72];
    const int r0 = blockIdx.x * 128, h = blockIdx.y;
    const int t = threadIdx.x;
    const int wave = t >> 6, lane = t & 63;
    const int lrow = lane & 15, lgrp = lane >> 4;

    #pragma unroll
    for (int i = 0; i < 4; ++i) {
        int c = t + i * 256, rr = c >> 3, off = (c & 7) * 8;
        *(us8*)&As[rr][off] = *(const us8*)(mid + (size_t)(r0 + rr) * HDIM + h*64 + off);
    }
    __syncthreads();
    bf16x8 af[2][2];
    #pragma unroll
    for (int m = 0; m < 2; ++m)
        #pragma unroll
        for (int kf = 0; kf < 2; ++kf)
            af[m][kf] = ldb(&As[wave*32 + m*16 + lrow][kf*32 + lgrp*8]);

    const unsigned short* ws[3] = {wq, wk, wv};
    const float* bs[3] = {bq, bk, bv};
    unsigned short* ds[3] = {q1, k1, v1};
    for (int o = 0; o < 3; ++o) {
        bf16x8 bfr[4][2];
        #pragma unroll
        for (int n = 0; n < 4; ++n)
            #pragma unroll
            for (int kf = 0; kf < 2; ++kf)
                bfr[n][kf] = __builtin_bit_cast(bf16x8,
                    *(const us8*)(ws[o] + (size_t)(n*16 + lrow) * 64 + kf*32 + lgrp*8));
        f32x4 acc[2][4];
        #pragma unroll
        for (int m = 0; m < 2; ++m)
            #pragma unroll
            for (int n = 0; n < 4; ++n) {
                f32x4 z = (f32x4){0.f, 0.f, 0.f, 0.f};
                z = mfma_bf16(af[m][0], bfr[n][0], z);
                z = mfma_bf16(af[m][1], bfr[n][1], z);
                acc[m][n] = z;
            }
        #pragma unroll
        for (int m = 0; m < 2; ++m)
            #pragma unroll
            for (int n = 0; n < 4; ++n) {
                float bb = bs[o][n*16 + lrow];
                #pragma unroll
                for (int q = 0; q < 4; ++q) {
                    int gr = r0 + wave*32 + m*16 + lgrp*4 + q;
                    int bi = gr / MIDL, seq = gr % MIDL;
                    size_t drow = (size_t)bi * TOT + 64 + seq;
                    ds[o][drow * HDIM + h*64 + n*16 + lrow] = f2bf(acc[m][n][q] + bb);
                }
            }
    }
}

__global__ __launch_bounds__(256) void k_copy_task(
    const unsigned short* __restrict__ q0, const unsigned short* __restrict__ k0,
    unsigned short* __restrict__ q1, unsigned short* __restrict__ k1,
    unsigned short* __restrict__ v1)
{
    int blk = blockIdx.x;
    int tensor = blk >> 7, rem = blk & 127;
    int b = rem >> 6, rr = rem & 63;
    const unsigned short* src = (tensor == 1) ? k0 : q0;
    unsigned short* dst = (tensor == 0) ? q1 : (tensor == 1 ? k1 : v1);
    size_t srow = (size_t)b * TOT + MIDL + rr;
    size_t drow = (size_t)b * TOT + rr;
    int t = threadIdx.x;
    if (t < 128)
        ((us8*)(dst + drow * HDIM))[t] = ((const us8*)(src + srow * HDIM))[t];
}

// ---------------------------------------------------------------- launcher
extern "C" void kernel_launch(void* const* d_in, const int* in_sizes, int n_in,
                              void* d_out, int out_size, void* d_ws, size_t ws_size,
                              hipStream_t stream)
{
    (void)in_sizes; (void)n_in; (void)out_size; (void)ws_size;
    const float* vis = (const float*)d_in[0];
    const float* txt = (const float*)d_in[1];
    const float* tsk = (const float*)d_in[2];
    const float* wq0 = (const float*)d_in[3];
    const float* bq0 = (const float*)d_in[4];
    const float* wk0 = (const float*)d_in[5];
    const float* bk0 = (const float*)d_in[6];
    const float* wv0 = (const float*)d_in[7];
    const float* bv0 = (const float*)d_in[8];
    const float* wq1 = (const float*)d_in[9];
    const float* bq1 = (const float*)d_in[10];
    const float* wk1 = (const float*)d_in[11];
    const float* bk1 = (const float*)d_in[12];
    const float* wv1 = (const float*)d_in[13];
    const float* bv1 = (const float*)d_in[14];
    const float* wo  = (const float*)d_in[15];
    const float* bo  = (const float*)d_in[16];

    char* ws = (char*)d_ws;
    size_t off = 0;
    auto carve = [&](size_t bytes) -> char* {
        char* p = ws + off;
        off += (bytes + 255) & ~(size_t)255;
        return p;
    };
    const size_t ELX = (size_t)NB * TOT * HDIM;
    unsigned short* X     = (unsigned short*)carve(ELX * 2);
    unsigned short* q0    = (unsigned short*)carve(ELX * 2);
    unsigned short* k0    = (unsigned short*)carve(ELX * 2);
    unsigned short* v0    = (unsigned short*)carve(ELX * 2);
    unsigned short* wqkvb = (unsigned short*)carve((size_t)3 * HDIM * HDIM * 2);
    unsigned short* wob   = (unsigned short*)carve((size_t)HDIM * HDIM * 2);
    unsigned short* wq1b  = (unsigned short*)carve(64 * 64 * 2);
    unsigned short* wk1b  = (unsigned short*)carve(64 * 64 * 2);
    unsigned short* wv1b  = (unsigned short*)carve(64 * 64 * 2);
    unsigned short* mid   = X;     // X dead after QKV GEMM
    unsigned short* q1    = q0;    // in-place stage-2 tensors
    unsigned short* k1    = k0;
    unsigned short* v1    = v0;
    unsigned short* out2  = X;     // mid dead after midlin

    const float scale = 1.0f / 64.0f;   // reference divides by d

    k_cast_hs<<<5120, 256, 0, stream>>>(vis, txt, tsk, X);
    k_cast<<<1024, 256, 0, stream>>>(wq0, wqkvb,                 HDIM * HDIM);
    k_cast<<<1024, 256, 0, stream>>>(wk0, wqkvb + 1024*1024,     HDIM * HDIM);
    k_cast<<<1024, 256, 0, stream>>>(wv0, wqkvb + 2*1024*1024,   HDIM * HDIM);
    k_cast<<<1024, 256, 0, stream>>>(wo,  wob,  HDIM * HDIM);
    k_cast<<<4, 256, 0, stream>>>(wq1, wq1b, 64 * 64);
    k_cast<<<4, 256, 0, stream>>>(wk1, wk1b, 64 * 64);
    k_cast<<<4, 256, 0, stream>>>(wv1, wv1b, 64 * 64);

    // Fused QKV projection: one dispatch, 960 blocks
    k_gemm_qkv<<<dim3(40, 24), 256, 0, stream>>>(
        X, wqkvb, bq0, bk0, bv0, q0, k0, v0);

    // v2t: Q=vision, K/V=text -> mid rows [0,2048)
    k_attn<<<dim3(VL/64, NHEAD, NB), 256, 0, stream>>>(
        q0, k0 + (size_t)VL * HDIM, v0 + (size_t)VL * HDIM, mid,
        TL, (size_t)TOT * HDIM, (size_t)TOT * HDIM, (size_t)MIDL * HDIM, scale);
    // t2v: Q=text, K/V=vision -> mid rows [2048,2496)
    k_attn<<<dim3(TL/64, NHEAD, NB), 256, 0, stream>>>(
        q0 + (size_t)VL * HDIM, k0, v0, mid + (size_t)VL * HDIM,
        VL, (size_t)TOT * HDIM, (size_t)TOT * HDIM, (size_t)MIDL * HDIM, scale);

    // task rows first (read-before-overwrite), then mid linear
    k_copy_task<<<384, 256, 0, stream>>>(q0, k0, q1, k1, v1);
    k_midlin<<<dim3(39, NHEAD), 256, 0, stream>>>(
        mid, wq1b, wk1b, wv1b, bq1, bk1, bv1, q1, k1, v1);

    // stage-2 attention over [task, v2t, t2v]
    k_attn<<<dim3(TOT/64, NHEAD, NB), 256, 0, stream>>>(
        q1, k1, v1, out2,
        TOT, (size_t)TOT * HDIM, (size_t)TOT * HDIM, (size_t)TOT * HDIM, scale);

    k_gemm_bt<false><<<dim3(40, 8), 256, 0, stream>>>(out2, wob, bo, (float*)d_out,
                                                      NB*TOT, HDIM, HDIM);
}

// Round 5
// 429.636 us; speedup vs baseline: 1.4811x; 1.1786x over previous
//
#include <hip/hip_runtime.h>
#include <math.h>

// Problem constants
#define NB   2
#define VL   2048
#define TL   448
#define KL   64
#define TOT  2560     // VL+TL+KL
#define MIDL 2496     // VL+TL
#define HDIM 1024
#define NHEAD 16
#define DHEAD 64

typedef __bf16 bf16x8 __attribute__((ext_vector_type(8)));
typedef float  f32x4  __attribute__((ext_vector_type(4)));
typedef unsigned short us8 __attribute__((ext_vector_type(8)));
typedef float  fl4    __attribute__((ext_vector_type(4)));
typedef unsigned int u32x2 __attribute__((ext_vector_type(2)));

__device__ __forceinline__ unsigned short f2bf(float f) {
    unsigned int u = __builtin_bit_cast(unsigned int, f);
    u += 0x7FFFu + ((u >> 16) & 1u);           // RNE
    return (unsigned short)(u >> 16);
}
__device__ __forceinline__ float bf2f(unsigned short u) {
    unsigned int x = ((unsigned int)u) << 16;
    return __builtin_bit_cast(float, x);
}
__device__ __forceinline__ f32x4 mfma_bf16(bf16x8 a, bf16x8 b, f32x4 c) {
    return __builtin_amdgcn_mfma_f32_16x16x32_bf16(a, b, c, 0, 0, 0);
}
__device__ __forceinline__ bf16x8 ldb(const unsigned short* p) {
    return __builtin_bit_cast(bf16x8, *(const us8*)p);
}

// ---------------------------------------------------------------- casts
__global__ __launch_bounds__(256) void k_cast_hs(
    const float* __restrict__ vis, const float* __restrict__ txt,
    const float* __restrict__ tsk, unsigned short* __restrict__ X)
{
    size_t idx = ((size_t)blockIdx.x * 256 + threadIdx.x) * 4;
    if (idx >= (size_t)NB * TOT * HDIM) return;
    size_t r = idx >> 10; int c = (int)(idx & 1023);
    int b = (int)(r / TOT), s = (int)(r % TOT);
    const float* src;
    if (s < VL)        src = vis + ((size_t)b * VL + s) * HDIM;
    else if (s < MIDL) src = txt + ((size_t)b * TL + (s - VL)) * HDIM;
    else               src = tsk + ((size_t)b * KL + (s - MIDL)) * HDIM;
    fl4 v = *(const fl4*)(src + c);
    X[idx + 0] = f2bf(v[0]); X[idx + 1] = f2bf(v[1]);
    X[idx + 2] = f2bf(v[2]); X[idx + 3] = f2bf(v[3]);
}

__global__ __launch_bounds__(256) void k_cast(
    const float* __restrict__ in, unsigned short* __restrict__ out, int n)
{
    int idx = (blockIdx.x * 256 + threadIdx.x) * 4;
    if (idx >= n) return;
    fl4 v = *(const fl4*)(in + idx);
    out[idx + 0] = f2bf(v[0]); out[idx + 1] = f2bf(v[1]);
    out[idx + 2] = f2bf(v[2]); out[idx + 3] = f2bf(v[3]);
}

// ---------------------------------------------------------------- GEMM (out-proj)
template<bool BF16OUT>
__global__ __launch_bounds__(256) void k_gemm_bt(
    const unsigned short* __restrict__ A, const unsigned short* __restrict__ W,
    const float* __restrict__ bias, void* __restrict__ Cv,
    int M, int N, int K)
{
    __shared__ unsigned short As[128][40];
    __shared__ unsigned short Bs[128][40];
    const int row0 = blockIdx.x * 128, col0 = blockIdx.y * 128;
    const int t = threadIdx.x;
    const int lane = t & 63, wave = t >> 6;
    const int wr = wave >> 1, wc = wave & 1;
    const int lrow = lane & 15, lgrp = lane >> 4;

    f32x4 acc[4][4];
    #pragma unroll
    for (int m = 0; m < 4; ++m)
        #pragma unroll
        for (int n = 0; n < 4; ++n)
            acc[m][n] = (f32x4){0.f, 0.f, 0.f, 0.f};

    const int r = t >> 1, hc = (t & 1) * 16;
    const unsigned short* Ap = A + (size_t)(row0 + r) * K + hc;
    const unsigned short* Wp = W + (size_t)(col0 + r) * K + hc;

    for (int kk = 0; kk < K; kk += 32) {
        us8 a0 = *(const us8*)(Ap + kk);
        us8 a1 = *(const us8*)(Ap + kk + 8);
        us8 b0 = *(const us8*)(Wp + kk);
        us8 b1 = *(const us8*)(Wp + kk + 8);
        __syncthreads();
        *(us8*)&As[r][hc]     = a0;
        *(us8*)&As[r][hc + 8] = a1;
        *(us8*)&Bs[r][hc]     = b0;
        *(us8*)&Bs[r][hc + 8] = b1;
        __syncthreads();
        bf16x8 af[4], bfr[4];
        #pragma unroll
        for (int m = 0; m < 4; ++m) af[m]  = ldb(&As[wr*64 + m*16 + lrow][lgrp*8]);
        #pragma unroll
        for (int n = 0; n < 4; ++n) bfr[n] = ldb(&Bs[wc*64 + n*16 + lrow][lgrp*8]);
        #pragma unroll
        for (int m = 0; m < 4; ++m)
            #pragma unroll
            for (int n = 0; n < 4; ++n)
                acc[m][n] = mfma_bf16(af[m], bfr[n], acc[m][n]);
    }
    #pragma unroll
    for (int m = 0; m < 4; ++m) {
        #pragma unroll
        for (int n = 0; n < 4; ++n) {
            int col = col0 + wc*64 + n*16 + lrow;
            float bs = bias[col];
            #pragma unroll
            for (int q = 0; q < 4; ++q) {
                int row = row0 + wr*64 + m*16 + lgrp*4 + q;
                float v = acc[m][n][q] + bs;
                if (BF16OUT) ((unsigned short*)Cv)[(size_t)row * N + col] = f2bf(v);
                else         ((float*)Cv)[(size_t)row * N + col] = v;
            }
        }
    }
}

// Fused QKV: M=5120, N=3072 (planes q|k|v), K=1024. W rows contiguous.
__global__ __launch_bounds__(256) void k_gemm_qkv(
    const unsigned short* __restrict__ A, const unsigned short* __restrict__ W,
    const float* __restrict__ b0, const float* __restrict__ b1,
    const float* __restrict__ b2,
    unsigned short* __restrict__ C0, unsigned short* __restrict__ C1,
    unsigned short* __restrict__ C2)
{
    __shared__ unsigned short As[128][40];
    __shared__ unsigned short Bs[128][40];
    const int row0 = blockIdx.x * 128, col0 = blockIdx.y * 128;
    const int t = threadIdx.x;
    const int lane = t & 63, wave = t >> 6;
    const int wr = wave >> 1, wc = wave & 1;
    const int lrow = lane & 15, lgrp = lane >> 4;

    f32x4 acc[4][4];
    #pragma unroll
    for (int m = 0; m < 4; ++m)
        #pragma unroll
        for (int n = 0; n < 4; ++n)
            acc[m][n] = (f32x4){0.f, 0.f, 0.f, 0.f};

    const int r = t >> 1, hc = (t & 1) * 16;
    const unsigned short* Ap = A + (size_t)(row0 + r) * HDIM + hc;
    const unsigned short* Wp = W + (size_t)(col0 + r) * HDIM + hc;

    for (int kk = 0; kk < HDIM; kk += 32) {
        us8 a0 = *(const us8*)(Ap + kk);
        us8 a1 = *(const us8*)(Ap + kk + 8);
        us8 b0v = *(const us8*)(Wp + kk);
        us8 b1v = *(const us8*)(Wp + kk + 8);
        __syncthreads();
        *(us8*)&As[r][hc]     = a0;
        *(us8*)&As[r][hc + 8] = a1;
        *(us8*)&Bs[r][hc]     = b0v;
        *(us8*)&Bs[r][hc + 8] = b1v;
        __syncthreads();
        bf16x8 af[4], bfr[4];
        #pragma unroll
        for (int m = 0; m < 4; ++m) af[m]  = ldb(&As[wr*64 + m*16 + lrow][lgrp*8]);
        #pragma unroll
        for (int n = 0; n < 4; ++n) bfr[n] = ldb(&Bs[wc*64 + n*16 + lrow][lgrp*8]);
        #pragma unroll
        for (int m = 0; m < 4; ++m)
            #pragma unroll
            for (int n = 0; n < 4; ++n)
                acc[m][n] = mfma_bf16(af[m], bfr[n], acc[m][n]);
    }
    const int plane = col0 >> 10;
    const float* bp = (plane == 0) ? b0 : (plane == 1) ? b1 : b2;
    unsigned short* Cp = (plane == 0) ? C0 : (plane == 1) ? C1 : C2;
    const int cl0 = col0 & 1023;
    #pragma unroll
    for (int m = 0; m < 4; ++m) {
        #pragma unroll
        for (int n = 0; n < 4; ++n) {
            int col = cl0 + wc*64 + n*16 + lrow;
            float bs = bp[col];
            #pragma unroll
            for (int q = 0; q < 4; ++q) {
                int row = row0 + wr*64 + m*16 + lgrp*4 + q;
                Cp[(size_t)row * HDIM + col] = f2bf(acc[m][n][q] + bs);
            }
        }
    }
}

// ---------------------------------------------------------------- attention
// Flash-style, grid (Lq/64, NHEAD, NB), 4 waves x 16 q-rows, scale = 1/64.
// SWAPPED QK^T: s = mfma(K,Q) -> S[key=lgrp*4+reg][q=lrow]; each lane owns
// one q-row (16 scores in-register). Softmax: 15 in-lane fmax + 2 shfl.
// P packed to LDS as 4x ds_write_b64 (conflict-free), read back as B-frag.
// PV in O^T form: mfma(A=Vt, B=P) -> O[q=lrow][d=lgrp*4+reg] -> 8B stores.
// V swizzle unchanged from R4 (verified conflict-free).
__global__ __launch_bounds__(256) void k_attn(
    const unsigned short* __restrict__ Qb, const unsigned short* __restrict__ Kb,
    const unsigned short* __restrict__ Vb, unsigned short* __restrict__ Ob,
    int Lk, size_t q_bs, size_t k_bs, size_t o_bs, float scale)
{
    __shared__ unsigned short QV[64 * 72];     // Qs[64][72], then swizzled Vt
    __shared__ unsigned short Ks[64][72];
    __shared__ unsigned short Pl[4][16][72];   // per-wave P[q=lrow][key]

    const int b = blockIdx.z, h = blockIdx.y, qb = blockIdx.x;
    const unsigned short* Q = Qb + (size_t)b * q_bs + h * 64;
    const unsigned short* K = Kb + (size_t)b * k_bs + h * 64;
    const unsigned short* V = Vb + (size_t)b * k_bs + h * 64;
    unsigned short*       O = Ob + (size_t)b * o_bs + h * 64;
    const int t = threadIdx.x;
    const int wave = t >> 6, lane = t & 63;
    const int lrow = lane & 15, lgrp = lane >> 4;
    const int q0r = qb * 64;

    #pragma unroll
    for (int i = 0; i < 2; ++i) {              // stage Q tile [64][64]
        int c = t + i * 256, rr = c >> 3, off = (c & 7) * 8;
        *(us8*)&QV[rr*72 + off] = *(const us8*)(Q + (size_t)(q0r + rr) * HDIM + off);
    }
    __syncthreads();
    bf16x8 qf0 = ldb(&QV[(wave*16 + lrow)*72 + lgrp*8]);
    bf16x8 qf1 = ldb(&QV[(wave*16 + lrow)*72 + 32 + lgrp*8]);
    // QV is reused as Vt after the first in-loop barrier (qf reads drained).

    f32x4 oacc[4];                             // oacc[df][r]=O[q=lrow][df*16+lgrp*4+r]
    #pragma unroll
    for (int d = 0; d < 4; ++d) oacc[d] = (f32x4){0.f, 0.f, 0.f, 0.f};
    float mr = -INFINITY;
    float lsum = 0.f;

    const int nkt = Lk >> 6;
    for (int kt = 0; kt < nkt; ++kt) {
        us8 kreg[2], vreg[2];
        #pragma unroll
        for (int i = 0; i < 2; ++i) {
            int c = t + i * 256, rr = c >> 3, off = (c & 7) * 8;
            kreg[i] = *(const us8*)(K + (size_t)(kt*64 + rr) * HDIM + off);
            vreg[i] = *(const us8*)(V + (size_t)(kt*64 + rr) * HDIM + off);
        }
        __syncthreads();                       // prior tile reads (and qf) done
        #pragma unroll
        for (int i = 0; i < 2; ++i) {
            int c = t + i * 256, rr = c >> 3, off = (c & 7) * 8;
            *(us8*)&Ks[rr][off] = kreg[i];
            int colp = (((rr >> 3) ^ (off >> 3)) << 3) + (rr & 7);
            #pragma unroll
            for (int j = 0; j < 8; ++j)
                QV[(off + j)*72 + colp] = vreg[i][j];
        }
        __syncthreads();

        // S^T = K Q^T : s[nf][reg] = S[key=nf*16+lgrp*4+reg][q=lrow] * scale
        f32x4 s[4];
        #pragma unroll
        for (int nf = 0; nf < 4; ++nf) {
            bf16x8 kf0 = ldb(&Ks[nf*16 + lrow][lgrp*8]);
            bf16x8 kf1 = ldb(&Ks[nf*16 + lrow][32 + lgrp*8]);
            f32x4 z = (f32x4){0.f, 0.f, 0.f, 0.f};
            z = mfma_bf16(kf0, qf0, z);        // swapped operands
            z = mfma_bf16(kf1, qf1, z);
            s[nf] = z * scale;
        }
        // online softmax: lane-local row; reduce across lgrp (masks 16,32)
        float mt = s[0][0];
        #pragma unroll
        for (int nf = 0; nf < 4; ++nf)
            #pragma unroll
            for (int r = 0; r < 4; ++r)
                mt = fmaxf(mt, s[nf][r]);
        mt = fmaxf(mt, __shfl_xor(mt, 16));
        mt = fmaxf(mt, __shfl_xor(mt, 32));
        float mn = fmaxf(mr, mt);
        float al = __expf(mr - mn);
        mr = mn;

        float rs = 0.f;
        #pragma unroll
        for (int nf = 0; nf < 4; ++nf) {
            unsigned short e0 = f2bf(__expf(s[nf][0] - mn));
            unsigned short e1 = f2bf(__expf(s[nf][1] - mn));
            unsigned short e2 = f2bf(__expf(s[nf][2] - mn));
            unsigned short e3 = f2bf(__expf(s[nf][3] - mn));
            rs += bf2f(e0) + bf2f(e1) + bf2f(e2) + bf2f(e3);
            u32x2 w;
            w[0] = (unsigned)e0 | ((unsigned)e1 << 16);
            w[1] = (unsigned)e2 | ((unsigned)e3 << 16);
            // keys nf*16 + lgrp*4 + 0..3, row q=lrow: one 8B write
            *(u32x2*)&Pl[wave][lrow][nf*16 + lgrp*4] = w;
        }
        rs += __shfl_xor(rs, 16);
        rs += __shfl_xor(rs, 32);
        lsum = lsum * al + rs;
        #pragma unroll
        for (int d = 0; d < 4; ++d) oacc[d] *= al;

        // PV (O^T form): A = Vt frags (swizzled reads), B = P frags
        bf16x8 pb0 = ldb(&Pl[wave][lrow][lgrp*8]);        // P[q=lrow][k=8lgrp+j]
        bf16x8 pb1 = ldb(&Pl[wave][lrow][32 + lgrp*8]);   // k=32+8lgrp+j
        #pragma unroll
        for (int df = 0; df < 4; ++df) {
            int d = df*16 + lrow;
            int f = (d >> 3) & 7;
            bf16x8 v0 = ldb(&QV[d*72 + ((lgrp ^ f) << 3)]);        // k=8lgrp+j
            bf16x8 v1 = ldb(&QV[d*72 + (((4 | lgrp) ^ f) << 3)]);  // k=32+8lgrp+j
            oacc[df] = mfma_bf16(v0, pb0, oacc[df]);
            oacc[df] = mfma_bf16(v1, pb1, oacc[df]);
        }
    }
    const float rcp = 1.0f / lsum;
    const int row = q0r + wave*16 + lrow;
    #pragma unroll
    for (int df = 0; df < 4; ++df) {
        unsigned short c0 = f2bf(oacc[df][0] * rcp);
        unsigned short c1 = f2bf(oacc[df][1] * rcp);
        unsigned short c2 = f2bf(oacc[df][2] * rcp);
        unsigned short c3 = f2bf(oacc[df][3] * rcp);
        u32x2 w;
        w[0] = (unsigned)c0 | ((unsigned)c1 << 16);
        w[1] = (unsigned)c2 | ((unsigned)c3 << 16);
        *(u32x2*)(O + (size_t)row * HDIM + df*16 + lgrp*4) = w;
    }
}

// ---------------------------------------------------------------- mid linear
__global__ __launch_bounds__(256) void k_midlin(
    const unsigned short* __restrict__ mid,
    const unsigned short* __restrict__ wq, const unsigned short* __restrict__ wk,
    const unsigned short* __restrict__ wv,
    const float* __restrict__ bq, const float* __restrict__ bk,
    const float* __restrict__ bv,
    unsigned short* __restrict__ q1, unsigned short* __restrict__ k1,
    unsigned short* __restrict__ v1)
{
    __shared__ unsigned short As[128][72];
    const int r0 = blockIdx.x * 128, h = blockIdx.y;
    const int t = threadIdx.x;
    const int wave = t >> 6, lane = t & 63;
    const int lrow = lane & 15, lgrp = lane >> 4;

    #pragma unroll
    for (int i = 0; i < 4; ++i) {
        int c = t + i * 256, rr = c >> 3, off = (c & 7) * 8;
        *(us8*)&As[rr][off] = *(const us8*)(mid + (size_t)(r0 + rr) * HDIM + h*64 + off);
    }
    __syncthreads();
    bf16x8 af[2][2];
    #pragma unroll
    for (int m = 0; m < 2; ++m)
        #pragma unroll
        for (int kf = 0; kf < 2; ++kf)
            af[m][kf] = ldb(&As[wave*32 + m*16 + lrow][kf*32 + lgrp*8]);

    const unsigned short* ws[3] = {wq, wk, wv};
    const float* bs[3] = {bq, bk, bv};
    unsigned short* ds[3] = {q1, k1, v1};
    for (int o = 0; o < 3; ++o) {
        bf16x8 bfr[4][2];
        #pragma unroll
        for (int n = 0; n < 4; ++n)
            #pragma unroll
            for (int kf = 0; kf < 2; ++kf)
                bfr[n][kf] = __builtin_bit_cast(bf16x8,
                    *(const us8*)(ws[o] + (size_t)(n*16 + lrow) * 64 + kf*32 + lgrp*8));
        f32x4 acc[2][4];
        #pragma unroll
        for (int m = 0; m < 2; ++m)
            #pragma unroll
            for (int n = 0; n < 4; ++n) {
                f32x4 z = (f32x4){0.f, 0.f, 0.f, 0.f};
                z = mfma_bf16(af[m][0], bfr[n][0], z);
                z = mfma_bf16(af[m][1], bfr[n][1], z);
                acc[m][n] = z;
            }
        #pragma unroll
        for (int m = 0; m < 2; ++m)
            #pragma unroll
            for (int n = 0; n < 4; ++n) {
                float bb = bs[o][n*16 + lrow];
                #pragma unroll
                for (int q = 0; q < 4; ++q) {
                    int gr = r0 + wave*32 + m*16 + lgrp*4 + q;
                    int bi = gr / MIDL, seq = gr % MIDL;
                    size_t drow = (size_t)bi * TOT + 64 + seq;
                    ds[o][drow * HDIM + h*64 + n*16 + lrow] = f2bf(acc[m][n][q] + bb);
                }
            }
    }
}

__global__ __launch_bounds__(256) void k_copy_task(
    const unsigned short* __restrict__ q0, const unsigned short* __restrict__ k0,
    unsigned short* __restrict__ q1, unsigned short* __restrict__ k1,
    unsigned short* __restrict__ v1)
{
    int blk = blockIdx.x;
    int tensor = blk >> 7, rem = blk & 127;
    int b = rem >> 6, rr = rem & 63;
    const unsigned short* src = (tensor == 1) ? k0 : q0;
    unsigned short* dst = (tensor == 0) ? q1 : (tensor == 1 ? k1 : v1);
    size_t srow = (size_t)b * TOT + MIDL + rr;
    size_t drow = (size_t)b * TOT + rr;
    int t = threadIdx.x;
    if (t < 128)
        ((us8*)(dst + drow * HDIM))[t] = ((const us8*)(src + srow * HDIM))[t];
}

// ---------------------------------------------------------------- launcher
extern "C" void kernel_launch(void* const* d_in, const int* in_sizes, int n_in,
                              void* d_out, int out_size, void* d_ws, size_t ws_size,
                              hipStream_t stream)
{
    (void)in_sizes; (void)n_in; (void)out_size; (void)ws_size;
    const float* vis = (const float*)d_in[0];
    const float* txt = (const float*)d_in[1];
    const float* tsk = (const float*)d_in[2];
    const float* wq0 = (const float*)d_in[3];
    const float* bq0 = (const float*)d_in[4];
    const float* wk0 = (const float*)d_in[5];
    const float* bk0 = (const float*)d_in[6];
    const float* wv0 = (const float*)d_in[7];
    const float* bv0 = (const float*)d_in[8];
    const float* wq1 = (const float*)d_in[9];
    const float* bq1 = (const float*)d_in[10];
    const float* wk1 = (const float*)d_in[11];
    const float* bk1 = (const float*)d_in[12];
    const float* wv1 = (const float*)d_in[13];
    const float* bv1 = (const float*)d_in[14];
    const float* wo  = (const float*)d_in[15];
    const float* bo  = (const float*)d_in[16];

    char* ws = (char*)d_ws;
    size_t off = 0;
    auto carve = [&](size_t bytes) -> char* {
        char* p = ws + off;
        off += (bytes + 255) & ~(size_t)255;
        return p;
    };
    const size_t ELX = (size_t)NB * TOT * HDIM;
    unsigned short* X     = (unsigned short*)carve(ELX * 2);
    unsigned short* q0    = (unsigned short*)carve(ELX * 2);
    unsigned short* k0    = (unsigned short*)carve(ELX * 2);
    unsigned short* v0    = (unsigned short*)carve(ELX * 2);
    unsigned short* wqkvb = (unsigned short*)carve((size_t)3 * HDIM * HDIM * 2);
    unsigned short* wob   = (unsigned short*)carve((size_t)HDIM * HDIM * 2);
    unsigned short* wq1b  = (unsigned short*)carve(64 * 64 * 2);
    unsigned short* wk1b  = (unsigned short*)carve(64 * 64 * 2);
    unsigned short* wv1b  = (unsigned short*)carve(64 * 64 * 2);
    unsigned short* mid   = X;     // X dead after QKV GEMM
    unsigned short* q1    = q0;    // in-place stage-2 tensors
    unsigned short* k1    = k0;
    unsigned short* v1    = v0;
    unsigned short* out2  = X;     // mid dead after midlin

    const float scale = 1.0f / 64.0f;   // reference divides by d

    k_cast_hs<<<5120, 256, 0, stream>>>(vis, txt, tsk, X);
    k_cast<<<1024, 256, 0, stream>>>(wq0, wqkvb,                 HDIM * HDIM);
    k_cast<<<1024, 256, 0, stream>>>(wk0, wqkvb + 1024*1024,     HDIM * HDIM);
    k_cast<<<1024, 256, 0, stream>>>(wv0, wqkvb + 2*1024*1024,   HDIM * HDIM);
    k_cast<<<1024, 256, 0, stream>>>(wo,  wob,  HDIM * HDIM);
    k_cast<<<4, 256, 0, stream>>>(wq1, wq1b, 64 * 64);
    k_cast<<<4, 256, 0, stream>>>(wk1, wk1b, 64 * 64);
    k_cast<<<4, 256, 0, stream>>>(wv1, wv1b, 64 * 64);

    // Fused QKV projection: one dispatch, 960 blocks
    k_gemm_qkv<<<dim3(40, 24), 256, 0, stream>>>(
        X, wqkvb, bq0, bk0, bv0, q0, k0, v0);

    // v2t: Q=vision, K/V=text -> mid rows [0,2048)
    k_attn<<<dim3(VL/64, NHEAD, NB), 256, 0, stream>>>(
        q0, k0 + (size_t)VL * HDIM, v0 + (size_t)VL * HDIM, mid,
        TL, (size_t)TOT * HDIM, (size_t)TOT * HDIM, (size_t)MIDL * HDIM, scale);
    // t2v: Q=text, K/V=vision -> mid rows [2048,2496)
    k_attn<<<dim3(TL/64, NHEAD, NB), 256, 0, stream>>>(
        q0 + (size_t)VL * HDIM, k0, v0, mid + (size_t)VL * HDIM,
        VL, (size_t)TOT * HDIM, (size_t)TOT * HDIM, (size_t)MIDL * HDIM, scale);

    // task rows first (read-before-overwrite), then mid linear
    k_copy_task<<<384, 256, 0, stream>>>(q0, k0, q1, k1, v1);
    k_midlin<<<dim3(39, NHEAD), 256, 0, stream>>>(
        mid, wq1b, wk1b, wv1b, bq1, bk1, bv1, q1, k1, v1);

    // stage-2 attention over [task, v2t, t2v]
    k_attn<<<dim3(TOT/64, NHEAD, NB), 256, 0, stream>>>(
        q1, k1, v1, out2,
        TOT, (size_t)TOT * HDIM, (size_t)TOT * HDIM, (size_t)TOT * HDIM, scale);

    k_gemm_bt<false><<<dim3(40, 8), 256, 0, stream>>>(out2, wob, bo, (float*)d_out,
                                                      NB*TOT, HDIM, HDIM);
}

// Round 6
// 410.958 us; speedup vs baseline: 1.5485x; 1.0454x over previous
//
#include <hip/hip_runtime.h>
#include <math.h>

// Problem constants
#define NB   2
#define VL   2048
#define TL   448
#define KL   64
#define TOT  2560     // VL+TL+KL
#define MIDL 2496     // VL+TL
#define HDIM 1024
#define NHEAD 16
#define DHEAD 64

typedef __bf16 bf16x8 __attribute__((ext_vector_type(8)));
typedef float  f32x4  __attribute__((ext_vector_type(4)));
typedef unsigned short us8 __attribute__((ext_vector_type(8)));
typedef float  fl4    __attribute__((ext_vector_type(4)));
typedef unsigned int u32x2 __attribute__((ext_vector_type(2)));

__device__ __forceinline__ unsigned short f2bf(float f) {
    unsigned int u = __builtin_bit_cast(unsigned int, f);
    u += 0x7FFFu + ((u >> 16) & 1u);           // RNE
    return (unsigned short)(u >> 16);
}
__device__ __forceinline__ float bf2f(unsigned short u) {
    unsigned int x = ((unsigned int)u) << 16;
    return __builtin_bit_cast(float, x);
}
__device__ __forceinline__ f32x4 mfma_bf16(bf16x8 a, bf16x8 b, f32x4 c) {
    return __builtin_amdgcn_mfma_f32_16x16x32_bf16(a, b, c, 0, 0, 0);
}
__device__ __forceinline__ bf16x8 ldb(const unsigned short* p) {
    return __builtin_bit_cast(bf16x8, *(const us8*)p);
}

// ---------------------------------------------------------------- casts
__global__ __launch_bounds__(256) void k_cast_hs(
    const float* __restrict__ vis, const float* __restrict__ txt,
    const float* __restrict__ tsk, unsigned short* __restrict__ X)
{
    size_t idx = ((size_t)blockIdx.x * 256 + threadIdx.x) * 4;
    if (idx >= (size_t)NB * TOT * HDIM) return;
    size_t r = idx >> 10; int c = (int)(idx & 1023);
    int b = (int)(r / TOT), s = (int)(r % TOT);
    const float* src;
    if (s < VL)        src = vis + ((size_t)b * VL + s) * HDIM;
    else if (s < MIDL) src = txt + ((size_t)b * TL + (s - VL)) * HDIM;
    else               src = tsk + ((size_t)b * KL + (s - MIDL)) * HDIM;
    fl4 v = *(const fl4*)(src + c);
    X[idx + 0] = f2bf(v[0]); X[idx + 1] = f2bf(v[1]);
    X[idx + 2] = f2bf(v[2]); X[idx + 3] = f2bf(v[3]);
}

__global__ __launch_bounds__(256) void k_cast(
    const float* __restrict__ in, unsigned short* __restrict__ out, int n)
{
    int idx = (blockIdx.x * 256 + threadIdx.x) * 4;
    if (idx >= n) return;
    fl4 v = *(const fl4*)(in + idx);
    out[idx + 0] = f2bf(v[0]); out[idx + 1] = f2bf(v[1]);
    out[idx + 2] = f2bf(v[2]); out[idx + 3] = f2bf(v[3]);
}

// ---------------------------------------------------------------- GEMM (out-proj)
template<bool BF16OUT>
__global__ __launch_bounds__(256) void k_gemm_bt(
    const unsigned short* __restrict__ A, const unsigned short* __restrict__ W,
    const float* __restrict__ bias, void* __restrict__ Cv,
    int M, int N, int K)
{
    __shared__ unsigned short As[128][40];
    __shared__ unsigned short Bs[128][40];
    const int row0 = blockIdx.x * 128, col0 = blockIdx.y * 128;
    const int t = threadIdx.x;
    const int lane = t & 63, wave = t >> 6;
    const int wr = wave >> 1, wc = wave & 1;
    const int lrow = lane & 15, lgrp = lane >> 4;

    f32x4 acc[4][4];
    #pragma unroll
    for (int m = 0; m < 4; ++m)
        #pragma unroll
        for (int n = 0; n < 4; ++n)
            acc[m][n] = (f32x4){0.f, 0.f, 0.f, 0.f};

    const int r = t >> 1, hc = (t & 1) * 16;
    const unsigned short* Ap = A + (size_t)(row0 + r) * K + hc;
    const unsigned short* Wp = W + (size_t)(col0 + r) * K + hc;

    for (int kk = 0; kk < K; kk += 32) {
        us8 a0 = *(const us8*)(Ap + kk);
        us8 a1 = *(const us8*)(Ap + kk + 8);
        us8 b0 = *(const us8*)(Wp + kk);
        us8 b1 = *(const us8*)(Wp + kk + 8);
        __syncthreads();
        *(us8*)&As[r][hc]     = a0;
        *(us8*)&As[r][hc + 8] = a1;
        *(us8*)&Bs[r][hc]     = b0;
        *(us8*)&Bs[r][hc + 8] = b1;
        __syncthreads();
        bf16x8 af[4], bfr[4];
        #pragma unroll
        for (int m = 0; m < 4; ++m) af[m]  = ldb(&As[wr*64 + m*16 + lrow][lgrp*8]);
        #pragma unroll
        for (int n = 0; n < 4; ++n) bfr[n] = ldb(&Bs[wc*64 + n*16 + lrow][lgrp*8]);
        #pragma unroll
        for (int m = 0; m < 4; ++m)
            #pragma unroll
            for (int n = 0; n < 4; ++n)
                acc[m][n] = mfma_bf16(af[m], bfr[n], acc[m][n]);
    }
    #pragma unroll
    for (int m = 0; m < 4; ++m) {
        #pragma unroll
        for (int n = 0; n < 4; ++n) {
            int col = col0 + wc*64 + n*16 + lrow;
            float bs = bias[col];
            #pragma unroll
            for (int q = 0; q < 4; ++q) {
                int row = row0 + wr*64 + m*16 + lgrp*4 + q;
                float v = acc[m][n][q] + bs;
                if (BF16OUT) ((unsigned short*)Cv)[(size_t)row * N + col] = f2bf(v);
                else         ((float*)Cv)[(size_t)row * N + col] = v;
            }
        }
    }
}

// Fused QKV: M=5120, N=3072 (planes q|k|v), K=1024. q/k row-major;
// v written TRANSPOSED per head: vT[(b*NHEAD+h)*64 + d][seq] (8B stores).
__global__ __launch_bounds__(256) void k_gemm_qkv(
    const unsigned short* __restrict__ A, const unsigned short* __restrict__ W,
    const float* __restrict__ b0, const float* __restrict__ b1,
    const float* __restrict__ b2,
    unsigned short* __restrict__ C0, unsigned short* __restrict__ C1,
    unsigned short* __restrict__ vT)
{
    __shared__ unsigned short As[128][40];
    __shared__ unsigned short Bs[128][40];
    const int row0 = blockIdx.x * 128, col0 = blockIdx.y * 128;
    const int t = threadIdx.x;
    const int lane = t & 63, wave = t >> 6;
    const int wr = wave >> 1, wc = wave & 1;
    const int lrow = lane & 15, lgrp = lane >> 4;

    f32x4 acc[4][4];
    #pragma unroll
    for (int m = 0; m < 4; ++m)
        #pragma unroll
        for (int n = 0; n < 4; ++n)
            acc[m][n] = (f32x4){0.f, 0.f, 0.f, 0.f};

    const int r = t >> 1, hc = (t & 1) * 16;
    const unsigned short* Ap = A + (size_t)(row0 + r) * HDIM + hc;
    const unsigned short* Wp = W + (size_t)(col0 + r) * HDIM + hc;

    for (int kk = 0; kk < HDIM; kk += 32) {
        us8 a0 = *(const us8*)(Ap + kk);
        us8 a1 = *(const us8*)(Ap + kk + 8);
        us8 b0v = *(const us8*)(Wp + kk);
        us8 b1v = *(const us8*)(Wp + kk + 8);
        __syncthreads();
        *(us8*)&As[r][hc]     = a0;
        *(us8*)&As[r][hc + 8] = a1;
        *(us8*)&Bs[r][hc]     = b0v;
        *(us8*)&Bs[r][hc + 8] = b1v;
        __syncthreads();
        bf16x8 af[4], bfr[4];
        #pragma unroll
        for (int m = 0; m < 4; ++m) af[m]  = ldb(&As[wr*64 + m*16 + lrow][lgrp*8]);
        #pragma unroll
        for (int n = 0; n < 4; ++n) bfr[n] = ldb(&Bs[wc*64 + n*16 + lrow][lgrp*8]);
        #pragma unroll
        for (int m = 0; m < 4; ++m)
            #pragma unroll
            for (int n = 0; n < 4; ++n)
                acc[m][n] = mfma_bf16(af[m], bfr[n], acc[m][n]);
    }
    const int plane = col0 >> 10;
    const int cl0 = col0 & 1023;
    if (plane < 2) {
        const float* bp = (plane == 0) ? b0 : b1;
        unsigned short* Cp = (plane == 0) ? C0 : C1;
        #pragma unroll
        for (int m = 0; m < 4; ++m)
            #pragma unroll
            for (int n = 0; n < 4; ++n) {
                int col = cl0 + wc*64 + n*16 + lrow;
                float bs = bp[col];
                #pragma unroll
                for (int q = 0; q < 4; ++q) {
                    int row = row0 + wr*64 + m*16 + lgrp*4 + q;
                    Cp[(size_t)row * HDIM + col] = f2bf(acc[m][n][q] + bs);
                }
            }
    } else {
        // v plane: transposed store. 4 accum elems = 4 consecutive seq.
        #pragma unroll
        for (int m = 0; m < 4; ++m)
            #pragma unroll
            for (int n = 0; n < 4; ++n) {
                int col = cl0 + wc*64 + n*16 + lrow;
                int hh = col >> 6, dd = col & 63;
                float bs = b2[col];
                int rowb = row0 + wr*64 + m*16 + lgrp*4;   // 4-aligned, no b-cross
                int bb = rowb / TOT, sq = rowb % TOT;
                unsigned short e0 = f2bf(acc[m][n][0] + bs);
                unsigned short e1 = f2bf(acc[m][n][1] + bs);
                unsigned short e2 = f2bf(acc[m][n][2] + bs);
                unsigned short e3 = f2bf(acc[m][n][3] + bs);
                u32x2 w;
                w[0] = (unsigned)e0 | ((unsigned)e1 << 16);
                w[1] = (unsigned)e2 | ((unsigned)e3 << 16);
                *(u32x2*)(vT + ((size_t)(bb*NHEAD + hh)*64 + dd)*TOT + sq) = w;
            }
    }
}

// ---------------------------------------------------------------- attention
// Flash-style, grid (Lq/64, NHEAD, NB), 4 waves x 16 q-rows, scale = 1/64.
// SWAPPED QK^T (lane owns one q-row); V comes PRE-TRANSPOSED from HBM:
// vT[(b*NH+h)*64+d][seq] -> LDS Vs[64 d][72] via vector us8 copies (no
// scatter, no swizzle). PV O^T form: mfma(A=V^T frag, B=P frag).
// T14 prefetch: tile t+1 global loads issue before tile t compute.
__global__ __launch_bounds__(256) void k_attn(
    const unsigned short* __restrict__ Qb, const unsigned short* __restrict__ Kb,
    const unsigned short* __restrict__ vT, unsigned short* __restrict__ Ob,
    int Lk, size_t q_bs, size_t k_bs, int v_seq0, size_t o_bs, float scale)
{
    __shared__ unsigned short QV[64 * 72];     // Qs[64][72], then Vs[64 d][72]
    __shared__ unsigned short Ks[64][72];
    __shared__ unsigned short Pl[4][16][72];   // per-wave P[q=lrow][key]

    const int b = blockIdx.z, h = blockIdx.y, qb = blockIdx.x;
    const unsigned short* Q = Qb + (size_t)b * q_bs + h * 64;
    const unsigned short* K = Kb + (size_t)b * k_bs + h * 64;
    const unsigned short* V = vT + ((size_t)(b*NHEAD + h) * 64) * TOT + v_seq0;
    unsigned short*       O = Ob + (size_t)b * o_bs + h * 64;
    const int t = threadIdx.x;
    const int wave = t >> 6, lane = t & 63;
    const int lrow = lane & 15, lgrp = lane >> 4;
    const int q0r = qb * 64;

    #pragma unroll
    for (int i = 0; i < 2; ++i) {              // stage Q tile [64][64]
        int c = t + i * 256, rr = c >> 3, off = (c & 7) * 8;
        *(us8*)&QV[rr*72 + off] = *(const us8*)(Q + (size_t)(q0r + rr) * HDIM + off);
    }
    __syncthreads();
    bf16x8 qf0 = ldb(&QV[(wave*16 + lrow)*72 + lgrp*8]);
    bf16x8 qf1 = ldb(&QV[(wave*16 + lrow)*72 + 32 + lgrp*8]);
    // QV reused as Vs after the first in-loop barrier (qf reads drained there).

    f32x4 oacc[4];                             // oacc[df][r]=O[q=lrow][df*16+lgrp*4+r]
    #pragma unroll
    for (int d = 0; d < 4; ++d) oacc[d] = (f32x4){0.f, 0.f, 0.f, 0.f};
    float mr = -INFINITY;
    float lsum = 0.f;

    // per-thread staging coordinates (two chunks)
    const int c0 = t,        rr0 = c0 >> 3, of0 = (c0 & 7) * 8;
    const int c1 = t + 256,  rr1 = c1 >> 3, of1 = (c1 & 7) * 8;
    const unsigned short* Kp0 = K + (size_t)rr0 * HDIM + of0;  // key rr0
    const unsigned short* Kp1 = K + (size_t)rr1 * HDIM + of1;
    const unsigned short* Vp0 = V + (size_t)rr0 * TOT + of0;   // d-row rr0
    const unsigned short* Vp1 = V + (size_t)rr1 * TOT + of1;

    const int nkt = Lk >> 6;
    us8 ka0 = *(const us8*)(Kp0);
    us8 ka1 = *(const us8*)(Kp1);
    us8 va0 = *(const us8*)(Vp0);
    us8 va1 = *(const us8*)(Vp1);

    for (int kt = 0; kt < nkt; ++kt) {
        __syncthreads();                       // prior tile reads (and qf) done
        *(us8*)&Ks[rr0][of0] = ka0;
        *(us8*)&Ks[rr1][of1] = ka1;
        *(us8*)&QV[rr0*72 + of0] = va0;        // Vs[d=rr][k=of..of+7]
        *(us8*)&QV[rr1*72 + of1] = va1;
        if (kt + 1 < nkt) {                    // T14: prefetch before compute
            ka0 = *(const us8*)(Kp0 + (size_t)(kt+1) * 64 * HDIM);
            ka1 = *(const us8*)(Kp1 + (size_t)(kt+1) * 64 * HDIM);
            va0 = *(const us8*)(Vp0 + (kt+1) * 64);
            va1 = *(const us8*)(Vp1 + (kt+1) * 64);
        }
        __syncthreads();

        // S^T = K Q^T : s[nf][reg] = S[key=nf*16+lgrp*4+reg][q=lrow] * scale
        f32x4 s[4];
        #pragma unroll
        for (int nf = 0; nf < 4; ++nf) {
            bf16x8 kf0 = ldb(&Ks[nf*16 + lrow][lgrp*8]);
            bf16x8 kf1 = ldb(&Ks[nf*16 + lrow][32 + lgrp*8]);
            f32x4 z = (f32x4){0.f, 0.f, 0.f, 0.f};
            z = mfma_bf16(kf0, qf0, z);        // swapped operands
            z = mfma_bf16(kf1, qf1, z);
            s[nf] = z * scale;
        }
        // online softmax: lane-local row; reduce across lgrp (masks 16,32)
        float mt = s[0][0];
        #pragma unroll
        for (int nf = 0; nf < 4; ++nf)
            #pragma unroll
            for (int rg = 0; rg < 4; ++rg)
                mt = fmaxf(mt, s[nf][rg]);
        mt = fmaxf(mt, __shfl_xor(mt, 16));
        mt = fmaxf(mt, __shfl_xor(mt, 32));
        float mn = fmaxf(mr, mt);
        float al = __expf(mr - mn);
        mr = mn;

        float rs = 0.f;
        #pragma unroll
        for (int nf = 0; nf < 4; ++nf) {
            unsigned short e0 = f2bf(__expf(s[nf][0] - mn));
            unsigned short e1 = f2bf(__expf(s[nf][1] - mn));
            unsigned short e2 = f2bf(__expf(s[nf][2] - mn));
            unsigned short e3 = f2bf(__expf(s[nf][3] - mn));
            rs += bf2f(e0) + bf2f(e1) + bf2f(e2) + bf2f(e3);
            u32x2 w;
            w[0] = (unsigned)e0 | ((unsigned)e1 << 16);
            w[1] = (unsigned)e2 | ((unsigned)e3 << 16);
            *(u32x2*)&Pl[wave][lrow][nf*16 + lgrp*4] = w;
        }
        rs += __shfl_xor(rs, 16);
        rs += __shfl_xor(rs, 32);
        lsum = lsum * al + rs;
        #pragma unroll
        for (int d = 0; d < 4; ++d) oacc[d] *= al;

        // PV (O^T form): A = V^T frags (clean rows), B = P frags
        bf16x8 pb0 = ldb(&Pl[wave][lrow][lgrp*8]);        // P[q=lrow][k=8lgrp+j]
        bf16x8 pb1 = ldb(&Pl[wave][lrow][32 + lgrp*8]);   // k=32+8lgrp+j
        #pragma unroll
        for (int df = 0; df < 4; ++df) {
            int d = df*16 + lrow;
            bf16x8 v0 = ldb(&QV[d*72 + lgrp*8]);          // V^T[d][k=8lgrp+j]
            bf16x8 v1 = ldb(&QV[d*72 + 32 + lgrp*8]);     // k=32+8lgrp+j
            oacc[df] = mfma_bf16(v0, pb0, oacc[df]);
            oacc[df] = mfma_bf16(v1, pb1, oacc[df]);
        }
    }
    const float rcp = 1.0f / lsum;
    const int row = q0r + wave*16 + lrow;
    #pragma unroll
    for (int df = 0; df < 4; ++df) {
        unsigned short e0 = f2bf(oacc[df][0] * rcp);
        unsigned short e1 = f2bf(oacc[df][1] * rcp);
        unsigned short e2 = f2bf(oacc[df][2] * rcp);
        unsigned short e3 = f2bf(oacc[df][3] * rcp);
        u32x2 w;
        w[0] = (unsigned)e0 | ((unsigned)e1 << 16);
        w[1] = (unsigned)e2 | ((unsigned)e3 << 16);
        *(u32x2*)(O + (size_t)row * HDIM + df*16 + lgrp*4) = w;
    }
}

// ---------------------------------------------------------------- mid linear
// q1/k1 row-major in place; v1 written transposed into vT (seq offset +64).
__global__ __launch_bounds__(256) void k_midlin(
    const unsigned short* __restrict__ mid,
    const unsigned short* __restrict__ wq, const unsigned short* __restrict__ wk,
    const unsigned short* __restrict__ wv,
    const float* __restrict__ bq, const float* __restrict__ bk,
    const float* __restrict__ bv,
    unsigned short* __restrict__ q1, unsigned short* __restrict__ k1,
    unsigned short* __restrict__ vT)
{
    __shared__ unsigned short As[128][72];
    const int r0 = blockIdx.x * 128, h = blockIdx.y;
    const int t = threadIdx.x;
    const int wave = t >> 6, lane = t & 63;
    const int lrow = lane & 15, lgrp = lane >> 4;

    #pragma unroll
    for (int i = 0; i < 4; ++i) {
        int c = t + i * 256, rr = c >> 3, off = (c & 7) * 8;
        *(us8*)&As[rr][off] = *(const us8*)(mid + (size_t)(r0 + rr) * HDIM + h*64 + off);
    }
    __syncthreads();
    bf16x8 af[2][2];
    #pragma unroll
    for (int m = 0; m < 2; ++m)
        #pragma unroll
        for (int kf = 0; kf < 2; ++kf)
            af[m][kf] = ldb(&As[wave*32 + m*16 + lrow][kf*32 + lgrp*8]);

    const unsigned short* ws[3] = {wq, wk, wv};
    const float* bs[3] = {bq, bk, bv};
    unsigned short* ds[2] = {q1, k1};
    #pragma unroll
    for (int o = 0; o < 3; ++o) {
        bf16x8 bfr[4][2];
        #pragma unroll
        for (int n = 0; n < 4; ++n)
            #pragma unroll
            for (int kf = 0; kf < 2; ++kf)
                bfr[n][kf] = __builtin_bit_cast(bf16x8,
                    *(const us8*)(ws[o] + (size_t)(n*16 + lrow) * 64 + kf*32 + lgrp*8));
        f32x4 acc[2][4];
        #pragma unroll
        for (int m = 0; m < 2; ++m)
            #pragma unroll
            for (int n = 0; n < 4; ++n) {
                f32x4 z = (f32x4){0.f, 0.f, 0.f, 0.f};
                z = mfma_bf16(af[m][0], bfr[n][0], z);
                z = mfma_bf16(af[m][1], bfr[n][1], z);
                acc[m][n] = z;
            }
        #pragma unroll
        for (int m = 0; m < 2; ++m)
            #pragma unroll
            for (int n = 0; n < 4; ++n) {
                float bb = bs[o][n*16 + lrow];
                if (o < 2) {
                    #pragma unroll
                    for (int q = 0; q < 4; ++q) {
                        int gr = r0 + wave*32 + m*16 + lgrp*4 + q;
                        int bi = gr / MIDL, sq = gr % MIDL;
                        size_t drow = (size_t)bi * TOT + 64 + sq;
                        ds[o][drow * HDIM + h*64 + n*16 + lrow] = f2bf(acc[m][n][q] + bb);
                    }
                } else {
                    int gr = r0 + wave*32 + m*16 + lgrp*4;   // 4-aligned, MIDL%4==0
                    int bi = gr / MIDL, sq = gr % MIDL;
                    unsigned short e0 = f2bf(acc[m][n][0] + bb);
                    unsigned short e1 = f2bf(acc[m][n][1] + bb);
                    unsigned short e2 = f2bf(acc[m][n][2] + bb);
                    unsigned short e3 = f2bf(acc[m][n][3] + bb);
                    u32x2 w;
                    w[0] = (unsigned)e0 | ((unsigned)e1 << 16);
                    w[1] = (unsigned)e2 | ((unsigned)e3 << 16);
                    *(u32x2*)(vT + ((size_t)(bi*NHEAD + h)*64 + (n*16+lrow))*TOT
                              + 64 + sq) = w;
                }
            }
    }
}

// Task rows: q1<-q0.task, k1<-k0.task (row copies); vT seq[0,64) <- q0.task
// TRANSPOSED (reference quirk: kv = q0 task slice).
__global__ __launch_bounds__(256) void k_copy_task(
    const unsigned short* __restrict__ q0, const unsigned short* __restrict__ k0,
    unsigned short* __restrict__ q1, unsigned short* __restrict__ k1,
    unsigned short* __restrict__ vT)
{
    int blk = blockIdx.x;
    int t = threadIdx.x;
    if (blk < 256) {
        int tensor = blk >> 7, rem = blk & 127;
        int b = rem >> 6, rr = rem & 63;
        const unsigned short* src = tensor ? k0 : q0;
        unsigned short* dst = tensor ? k1 : q1;
        size_t srow = (size_t)b * TOT + MIDL + rr;
        size_t drow = (size_t)b * TOT + rr;
        if (t < 128)
            ((us8*)(dst + drow * HDIM))[t] = ((const us8*)(src + srow * HDIM))[t];
    } else {
        int rem = blk - 256;                  // 32 blocks: b(2) x h(16)
        int b = rem >> 4, h = rem & 15;
        const unsigned short* src = q0 + ((size_t)b * TOT + MIDL) * HDIM + h * 64;
        unsigned short* dst = vT + ((size_t)(b*NHEAD + h) * 64) * TOT;
        #pragma unroll
        for (int i = 0; i < 16; ++i) {
            int idx = t + i * 256;            // 4096 elems: r=idx&63, d=idx>>6
            int r = idx & 63, d = idx >> 6;
            dst[(size_t)d * TOT + r] = src[(size_t)r * HDIM + d];
        }
    }
}

// ---------------------------------------------------------------- launcher
extern "C" void kernel_launch(void* const* d_in, const int* in_sizes, int n_in,
                              void* d_out, int out_size, void* d_ws, size_t ws_size,
                              hipStream_t stream)
{
    (void)in_sizes; (void)n_in; (void)out_size; (void)ws_size;
    const float* vis = (const float*)d_in[0];
    const float* txt = (const float*)d_in[1];
    const float* tsk = (const float*)d_in[2];
    const float* wq0 = (const float*)d_in[3];
    const float* bq0 = (const float*)d_in[4];
    const float* wk0 = (const float*)d_in[5];
    const float* bk0 = (const float*)d_in[6];
    const float* wv0 = (const float*)d_in[7];
    const float* bv0 = (const float*)d_in[8];
    const float* wq1 = (const float*)d_in[9];
    const float* bq1 = (const float*)d_in[10];
    const float* wk1 = (const float*)d_in[11];
    const float* bk1 = (const float*)d_in[12];
    const float* wv1 = (const float*)d_in[13];
    const float* bv1 = (const float*)d_in[14];
    const float* wo  = (const float*)d_in[15];
    const float* bo  = (const float*)d_in[16];

    char* ws = (char*)d_ws;
    size_t off = 0;
    auto carve = [&](size_t bytes) -> char* {
        char* p = ws + off;
        off += (bytes + 255) & ~(size_t)255;
        return p;
    };
    const size_t ELX = (size_t)NB * TOT * HDIM;
    unsigned short* X     = (unsigned short*)carve(ELX * 2);
    unsigned short* q0    = (unsigned short*)carve(ELX * 2);
    unsigned short* k0    = (unsigned short*)carve(ELX * 2);
    unsigned short* vT    = (unsigned short*)carve(ELX * 2);  // [b][h][d][seq]
    unsigned short* wqkvb = (unsigned short*)carve((size_t)3 * HDIM * HDIM * 2);
    unsigned short* wob   = (unsigned short*)carve((size_t)HDIM * HDIM * 2);
    unsigned short* wq1b  = (unsigned short*)carve(64 * 64 * 2);
    unsigned short* wk1b  = (unsigned short*)carve(64 * 64 * 2);
    unsigned short* wv1b  = (unsigned short*)carve(64 * 64 * 2);
    unsigned short* mid   = X;     // X dead after QKV GEMM
    unsigned short* q1    = q0;    // in-place stage-2 tensors
    unsigned short* k1    = k0;
    unsigned short* out2  = X;     // mid dead after midlin

    const float scale = 1.0f / 64.0f;   // reference divides by d

    k_cast_hs<<<5120, 256, 0, stream>>>(vis, txt, tsk, X);
    k_cast<<<1024, 256, 0, stream>>>(wq0, wqkvb,                 HDIM * HDIM);
    k_cast<<<1024, 256, 0, stream>>>(wk0, wqkvb + 1024*1024,     HDIM * HDIM);
    k_cast<<<1024, 256, 0, stream>>>(wv0, wqkvb + 2*1024*1024,   HDIM * HDIM);
    k_cast<<<1024, 256, 0, stream>>>(wo,  wob,  HDIM * HDIM);
    k_cast<<<4, 256, 0, stream>>>(wq1, wq1b, 64 * 64);
    k_cast<<<4, 256, 0, stream>>>(wk1, wk1b, 64 * 64);
    k_cast<<<4, 256, 0, stream>>>(wv1, wv1b, 64 * 64);

    // Fused QKV projection (v plane transposed)
    k_gemm_qkv<<<dim3(40, 24), 256, 0, stream>>>(
        X, wqkvb, bq0, bk0, bv0, q0, k0, vT);

    // v2t: Q=vision, K=text rows, V=text seqs -> mid rows [0,2048)
    k_attn<<<dim3(VL/64, NHEAD, NB), 256, 0, stream>>>(
        q0, k0 + (size_t)VL * HDIM, vT, mid,
        TL, (size_t)TOT * HDIM, (size_t)TOT * HDIM, VL, (size_t)MIDL * HDIM, scale);
    // t2v: Q=text, K=vision rows, V=vision seqs -> mid rows [2048,2496)
    k_attn<<<dim3(TL/64, NHEAD, NB), 256, 0, stream>>>(
        q0 + (size_t)VL * HDIM, k0, vT, mid + (size_t)VL * HDIM,
        VL, (size_t)TOT * HDIM, (size_t)TOT * HDIM, 0, (size_t)MIDL * HDIM, scale);

    // task rows (reads q0/k0 task before midlin overwrites), then mid linear
    k_copy_task<<<288, 256, 0, stream>>>(q0, k0, q1, k1, vT);
    k_midlin<<<dim3(39, NHEAD), 256, 0, stream>>>(
        mid, wq1b, wk1b, wv1b, bq1, bk1, bv1, q1, k1, vT);

    // stage-2 attention over [task, v2t, t2v]
    k_attn<<<dim3(TOT/64, NHEAD, NB), 256, 0, stream>>>(
        q1, k1, vT, out2,
        TOT, (size_t)TOT * HDIM, (size_t)TOT * HDIM, 0, (size_t)TOT * HDIM, scale);

    k_gemm_bt<false><<<dim3(40, 8), 256, 0, stream>>>(out2, wob, bo, (float*)d_out,
                                                      NB*TOT, HDIM, HDIM);
}

// Round 7
// 389.547 us; speedup vs baseline: 1.6336x; 1.0550x over previous
//
#include <hip/hip_runtime.h>
#include <math.h>

// Problem constants
#define NB   2
#define VL   2048
#define TL   448
#define KL   64
#define TOT  2560     // VL+TL+KL
#define MIDL 2496     // VL+TL
#define HDIM 1024
#define NHEAD 16
#define DHEAD 64

typedef __bf16 bf16x8 __attribute__((ext_vector_type(8)));
typedef float  f32x4  __attribute__((ext_vector_type(4)));
typedef unsigned short us8 __attribute__((ext_vector_type(8)));
typedef float  fl4    __attribute__((ext_vector_type(4)));
typedef unsigned int u32x2 __attribute__((ext_vector_type(2)));

__device__ __forceinline__ unsigned short f2bf(float f) {
    unsigned int u = __builtin_bit_cast(unsigned int, f);
    u += 0x7FFFu + ((u >> 16) & 1u);           // RNE
    return (unsigned short)(u >> 16);
}
__device__ __forceinline__ f32x4 mfma_bf16(bf16x8 a, bf16x8 b, f32x4 c) {
    return __builtin_amdgcn_mfma_f32_16x16x32_bf16(a, b, c, 0, 0, 0);
}
__device__ __forceinline__ bf16x8 ldb(const unsigned short* p) {
    return __builtin_bit_cast(bf16x8, *(const us8*)p);
}
// packed f32x2 -> bf16x2 (RNE), T12 recipe
__device__ __forceinline__ unsigned cvt_pk_bf16(float lo, float hi) {
    unsigned r;
    asm("v_cvt_pk_bf16_f32 %0, %1, %2" : "=v"(r) : "v"(lo), "v"(hi));
    return r;
}
__device__ __forceinline__ float exp2_fast(float x) {   // 2^x, raw v_exp
    float r;
    asm("v_exp_f32 %0, %1" : "=v"(r) : "v"(x));
    return r;
}

// ---------------------------------------------------------------- casts
__global__ __launch_bounds__(256) void k_cast_hs(
    const float* __restrict__ vis, const float* __restrict__ txt,
    const float* __restrict__ tsk, unsigned short* __restrict__ X)
{
    size_t idx = ((size_t)blockIdx.x * 256 + threadIdx.x) * 4;
    if (idx >= (size_t)NB * TOT * HDIM) return;
    size_t r = idx >> 10; int c = (int)(idx & 1023);
    int b = (int)(r / TOT), s = (int)(r % TOT);
    const float* src;
    if (s < VL)        src = vis + ((size_t)b * VL + s) * HDIM;
    else if (s < MIDL) src = txt + ((size_t)b * TL + (s - VL)) * HDIM;
    else               src = tsk + ((size_t)b * KL + (s - MIDL)) * HDIM;
    fl4 v = *(const fl4*)(src + c);
    X[idx + 0] = f2bf(v[0]); X[idx + 1] = f2bf(v[1]);
    X[idx + 2] = f2bf(v[2]); X[idx + 3] = f2bf(v[3]);
}

__global__ __launch_bounds__(256) void k_cast(
    const float* __restrict__ in, unsigned short* __restrict__ out, int n)
{
    int idx = (blockIdx.x * 256 + threadIdx.x) * 4;
    if (idx >= n) return;
    fl4 v = *(const fl4*)(in + idx);
    out[idx + 0] = f2bf(v[0]); out[idx + 1] = f2bf(v[1]);
    out[idx + 2] = f2bf(v[2]); out[idx + 3] = f2bf(v[3]);
}

// ---------------------------------------------------------------- GEMM (out-proj)
template<bool BF16OUT>
__global__ __launch_bounds__(256) void k_gemm_bt(
    const unsigned short* __restrict__ A, const unsigned short* __restrict__ W,
    const float* __restrict__ bias, void* __restrict__ Cv,
    int M, int N, int K)
{
    __shared__ unsigned short As[128][40];
    __shared__ unsigned short Bs[128][40];
    const int row0 = blockIdx.x * 128, col0 = blockIdx.y * 128;
    const int t = threadIdx.x;
    const int lane = t & 63, wave = t >> 6;
    const int wr = wave >> 1, wc = wave & 1;
    const int lrow = lane & 15, lgrp = lane >> 4;

    f32x4 acc[4][4];
    #pragma unroll
    for (int m = 0; m < 4; ++m)
        #pragma unroll
        for (int n = 0; n < 4; ++n)
            acc[m][n] = (f32x4){0.f, 0.f, 0.f, 0.f};

    const int r = t >> 1, hc = (t & 1) * 16;
    const unsigned short* Ap = A + (size_t)(row0 + r) * K + hc;
    const unsigned short* Wp = W + (size_t)(col0 + r) * K + hc;

    for (int kk = 0; kk < K; kk += 32) {
        us8 a0 = *(const us8*)(Ap + kk);
        us8 a1 = *(const us8*)(Ap + kk + 8);
        us8 b0 = *(const us8*)(Wp + kk);
        us8 b1 = *(const us8*)(Wp + kk + 8);
        __syncthreads();
        *(us8*)&As[r][hc]     = a0;
        *(us8*)&As[r][hc + 8] = a1;
        *(us8*)&Bs[r][hc]     = b0;
        *(us8*)&Bs[r][hc + 8] = b1;
        __syncthreads();
        bf16x8 af[4], bfr[4];
        #pragma unroll
        for (int m = 0; m < 4; ++m) af[m]  = ldb(&As[wr*64 + m*16 + lrow][lgrp*8]);
        #pragma unroll
        for (int n = 0; n < 4; ++n) bfr[n] = ldb(&Bs[wc*64 + n*16 + lrow][lgrp*8]);
        #pragma unroll
        for (int m = 0; m < 4; ++m)
            #pragma unroll
            for (int n = 0; n < 4; ++n)
                acc[m][n] = mfma_bf16(af[m], bfr[n], acc[m][n]);
    }
    #pragma unroll
    for (int m = 0; m < 4; ++m) {
        #pragma unroll
        for (int n = 0; n < 4; ++n) {
            int col = col0 + wc*64 + n*16 + lrow;
            float bs = bias[col];
            #pragma unroll
            for (int q = 0; q < 4; ++q) {
                int row = row0 + wr*64 + m*16 + lgrp*4 + q;
                float v = acc[m][n][q] + bs;
                if (BF16OUT) ((unsigned short*)Cv)[(size_t)row * N + col] = f2bf(v);
                else         ((float*)Cv)[(size_t)row * N + col] = v;
            }
        }
    }
}

// Fused QKV: M=5120, N=3072 (planes q|k|v), K=1024. q/k row-major;
// v written TRANSPOSED per head: vT[(b*NHEAD+h)*64 + d][seq] (8B stores).
__global__ __launch_bounds__(256) void k_gemm_qkv(
    const unsigned short* __restrict__ A, const unsigned short* __restrict__ W,
    const float* __restrict__ b0, const float* __restrict__ b1,
    const float* __restrict__ b2,
    unsigned short* __restrict__ C0, unsigned short* __restrict__ C1,
    unsigned short* __restrict__ vT)
{
    __shared__ unsigned short As[128][40];
    __shared__ unsigned short Bs[128][40];
    const int row0 = blockIdx.x * 128, col0 = blockIdx.y * 128;
    const int t = threadIdx.x;
    const int lane = t & 63, wave = t >> 6;
    const int wr = wave >> 1, wc = wave & 1;
    const int lrow = lane & 15, lgrp = lane >> 4;

    f32x4 acc[4][4];
    #pragma unroll
    for (int m = 0; m < 4; ++m)
        #pragma unroll
        for (int n = 0; n < 4; ++n)
            acc[m][n] = (f32x4){0.f, 0.f, 0.f, 0.f};

    const int r = t >> 1, hc = (t & 1) * 16;
    const unsigned short* Ap = A + (size_t)(row0 + r) * HDIM + hc;
    const unsigned short* Wp = W + (size_t)(col0 + r) * HDIM + hc;

    for (int kk = 0; kk < HDIM; kk += 32) {
        us8 a0 = *(const us8*)(Ap + kk);
        us8 a1 = *(const us8*)(Ap + kk + 8);
        us8 b0v = *(const us8*)(Wp + kk);
        us8 b1v = *(const us8*)(Wp + kk + 8);
        __syncthreads();
        *(us8*)&As[r][hc]     = a0;
        *(us8*)&As[r][hc + 8] = a1;
        *(us8*)&Bs[r][hc]     = b0v;
        *(us8*)&Bs[r][hc + 8] = b1v;
        __syncthreads();
        bf16x8 af[4], bfr[4];
        #pragma unroll
        for (int m = 0; m < 4; ++m) af[m]  = ldb(&As[wr*64 + m*16 + lrow][lgrp*8]);
        #pragma unroll
        for (int n = 0; n < 4; ++n) bfr[n] = ldb(&Bs[wc*64 + n*16 + lrow][lgrp*8]);
        #pragma unroll
        for (int m = 0; m < 4; ++m)
            #pragma unroll
            for (int n = 0; n < 4; ++n)
                acc[m][n] = mfma_bf16(af[m], bfr[n], acc[m][n]);
    }
    const int plane = col0 >> 10;
    const int cl0 = col0 & 1023;
    if (plane < 2) {
        const float* bp = (plane == 0) ? b0 : b1;
        unsigned short* Cp = (plane == 0) ? C0 : C1;
        #pragma unroll
        for (int m = 0; m < 4; ++m)
            #pragma unroll
            for (int n = 0; n < 4; ++n) {
                int col = cl0 + wc*64 + n*16 + lrow;
                float bs = bp[col];
                #pragma unroll
                for (int q = 0; q < 4; ++q) {
                    int row = row0 + wr*64 + m*16 + lgrp*4 + q;
                    Cp[(size_t)row * HDIM + col] = f2bf(acc[m][n][q] + bs);
                }
            }
    } else {
        // v plane: transposed store. 4 accum elems = 4 consecutive seq.
        #pragma unroll
        for (int m = 0; m < 4; ++m)
            #pragma unroll
            for (int n = 0; n < 4; ++n) {
                int col = cl0 + wc*64 + n*16 + lrow;
                int hh = col >> 6, dd = col & 63;
                float bs = b2[col];
                int rowb = row0 + wr*64 + m*16 + lgrp*4;   // 4-aligned, no b-cross
                int bb = rowb / TOT, sq = rowb % TOT;
                u32x2 w;
                w[0] = cvt_pk_bf16(acc[m][n][0] + bs, acc[m][n][1] + bs);
                w[1] = cvt_pk_bf16(acc[m][n][2] + bs, acc[m][n][3] + bs);
                *(u32x2*)(vT + ((size_t)(bb*NHEAD + hh)*64 + dd)*TOT + sq) = w;
            }
    }
}

// ---------------------------------------------------------------- attention
// Flash-style, grid (Lq/64, NHEAD, NB), 4 waves x 16 q-rows.
// scale folds 1/64 AND log2(e): softmax runs in exp2 domain.
// SWAPPED QK^T (lane owns one q-row); V PRE-TRANSPOSED in HBM.
// T13 defer-max (THR=8, __all) skips the O-rescale on most tiles.
// P quantization via v_cvt_pk_bf16_f32 (8 cvt_pk replaces 16 f2bf+8 packs).
__global__ __launch_bounds__(256) void k_attn(
    const unsigned short* __restrict__ Qb, const unsigned short* __restrict__ Kb,
    const unsigned short* __restrict__ vT, unsigned short* __restrict__ Ob,
    int Lk, size_t q_bs, size_t k_bs, int v_seq0, size_t o_bs, float scale)
{
    __shared__ unsigned short QV[64 * 72];     // Qs[64][72], then Vs[64 d][72]
    __shared__ unsigned short Ks[64][72];
    __shared__ unsigned short Pl[4][16][72];   // per-wave P[q=lrow][key]

    const int b = blockIdx.z, h = blockIdx.y, qb = blockIdx.x;
    const unsigned short* Q = Qb + (size_t)b * q_bs + h * 64;
    const unsigned short* K = Kb + (size_t)b * k_bs + h * 64;
    const unsigned short* V = vT + ((size_t)(b*NHEAD + h) * 64) * TOT + v_seq0;
    unsigned short*       O = Ob + (size_t)b * o_bs + h * 64;
    const int t = threadIdx.x;
    const int wave = t >> 6, lane = t & 63;
    const int lrow = lane & 15, lgrp = lane >> 4;
    const int q0r = qb * 64;

    #pragma unroll
    for (int i = 0; i < 2; ++i) {              // stage Q tile [64][64]
        int c = t + i * 256, rr = c >> 3, off = (c & 7) * 8;
        *(us8*)&QV[rr*72 + off] = *(const us8*)(Q + (size_t)(q0r + rr) * HDIM + off);
    }
    __syncthreads();
    bf16x8 qf0 = ldb(&QV[(wave*16 + lrow)*72 + lgrp*8]);
    bf16x8 qf1 = ldb(&QV[(wave*16 + lrow)*72 + 32 + lgrp*8]);
    // QV reused as Vs after the first in-loop barrier (qf reads drained there).

    f32x4 oacc[4];                             // oacc[df][r]=O[q=lrow][df*16+lgrp*4+r]
    #pragma unroll
    for (int d = 0; d < 4; ++d) oacc[d] = (f32x4){0.f, 0.f, 0.f, 0.f};
    float mr = -INFINITY;
    float lsum = 0.f;

    // per-thread staging coordinates (two chunks)
    const int c0 = t,        rr0 = c0 >> 3, of0 = (c0 & 7) * 8;
    const int c1 = t + 256,  rr1 = c1 >> 3, of1 = (c1 & 7) * 8;
    const unsigned short* Kp0 = K + (size_t)rr0 * HDIM + of0;  // key rr0
    const unsigned short* Kp1 = K + (size_t)rr1 * HDIM + of1;
    const unsigned short* Vp0 = V + (size_t)rr0 * TOT + of0;   // d-row rr0
    const unsigned short* Vp1 = V + (size_t)rr1 * TOT + of1;

    const int nkt = Lk >> 6;
    us8 ka0 = *(const us8*)(Kp0);
    us8 ka1 = *(const us8*)(Kp1);
    us8 va0 = *(const us8*)(Vp0);
    us8 va1 = *(const us8*)(Vp1);

    for (int kt = 0; kt < nkt; ++kt) {
        __syncthreads();                       // prior tile reads (and qf) done
        *(us8*)&Ks[rr0][of0] = ka0;
        *(us8*)&Ks[rr1][of1] = ka1;
        *(us8*)&QV[rr0*72 + of0] = va0;        // Vs[d=rr][k=of..of+7]
        *(us8*)&QV[rr1*72 + of1] = va1;
        if (kt + 1 < nkt) {                    // T14: prefetch before compute
            ka0 = *(const us8*)(Kp0 + (size_t)(kt+1) * 64 * HDIM);
            ka1 = *(const us8*)(Kp1 + (size_t)(kt+1) * 64 * HDIM);
            va0 = *(const us8*)(Vp0 + (kt+1) * 64);
            va1 = *(const us8*)(Vp1 + (kt+1) * 64);
        }
        __syncthreads();

        // S^T = K Q^T : s[nf][reg] = S[key=nf*16+lgrp*4+reg][q=lrow] (log2 dom)
        f32x4 s[4];
        #pragma unroll
        for (int nf = 0; nf < 4; ++nf) {
            bf16x8 kf0 = ldb(&Ks[nf*16 + lrow][lgrp*8]);
            bf16x8 kf1 = ldb(&Ks[nf*16 + lrow][32 + lgrp*8]);
            f32x4 z = (f32x4){0.f, 0.f, 0.f, 0.f};
            z = mfma_bf16(kf0, qf0, z);        // swapped operands
            z = mfma_bf16(kf1, qf1, z);
            s[nf] = z * scale;
        }
        // online softmax (exp2 domain): lane-local row, reduce via 2 shfl
        float mt = s[0][0];
        #pragma unroll
        for (int nf = 0; nf < 4; ++nf)
            #pragma unroll
            for (int rg = 0; rg < 4; ++rg)
                mt = fmaxf(mt, s[nf][rg]);
        mt = fmaxf(mt, __shfl_xor(mt, 16));
        mt = fmaxf(mt, __shfl_xor(mt, 32));
        if (!__all(mt <= mr + 8.f)) {          // T13 defer-max
            float mnew = fmaxf(mr, mt);
            float al = exp2_fast(mr - mnew);
            mr = mnew;
            lsum *= al;
            #pragma unroll
            for (int d = 0; d < 4; ++d) oacc[d] *= al;
        }

        float rs = 0.f;
        #pragma unroll
        for (int nf = 0; nf < 4; ++nf) {
            float p0 = exp2_fast(s[nf][0] - mr);
            float p1 = exp2_fast(s[nf][1] - mr);
            float p2 = exp2_fast(s[nf][2] - mr);
            float p3 = exp2_fast(s[nf][3] - mr);
            rs += (p0 + p1) + (p2 + p3);
            u32x2 w;
            w[0] = cvt_pk_bf16(p0, p1);
            w[1] = cvt_pk_bf16(p2, p3);
            *(u32x2*)&Pl[wave][lrow][nf*16 + lgrp*4] = w;
        }
        rs += __shfl_xor(rs, 16);
        rs += __shfl_xor(rs, 32);
        lsum += rs;

        // PV (O^T form): A = V^T frags (clean rows), B = P frags
        bf16x8 pb0 = ldb(&Pl[wave][lrow][lgrp*8]);        // P[q=lrow][k=8lgrp+j]
        bf16x8 pb1 = ldb(&Pl[wave][lrow][32 + lgrp*8]);   // k=32+8lgrp+j
        #pragma unroll
        for (int df = 0; df < 4; ++df) {
            int d = df*16 + lrow;
            bf16x8 v0 = ldb(&QV[d*72 + lgrp*8]);          // V^T[d][k=8lgrp+j]
            bf16x8 v1 = ldb(&QV[d*72 + 32 + lgrp*8]);     // k=32+8lgrp+j
            oacc[df] = mfma_bf16(v0, pb0, oacc[df]);
            oacc[df] = mfma_bf16(v1, pb1, oacc[df]);
        }
    }
    const float rcp = 1.0f / lsum;
    const int row = q0r + wave*16 + lrow;
    #pragma unroll
    for (int df = 0; df < 4; ++df) {
        u32x2 w;
        w[0] = cvt_pk_bf16(oacc[df][0] * rcp, oacc[df][1] * rcp);
        w[1] = cvt_pk_bf16(oacc[df][2] * rcp, oacc[df][3] * rcp);
        *(u32x2*)(O + (size_t)row * HDIM + df*16 + lgrp*4) = w;
    }
}

// ---------------------------------------------------------------- mid linear
// q1/k1 row-major in place; v1 written transposed into vT (seq offset +64).
__global__ __launch_bounds__(256) void k_midlin(
    const unsigned short* __restrict__ mid,
    const unsigned short* __restrict__ wq, const unsigned short* __restrict__ wk,
    const unsigned short* __restrict__ wv,
    const float* __restrict__ bq, const float* __restrict__ bk,
    const float* __restrict__ bv,
    unsigned short* __restrict__ q1, unsigned short* __restrict__ k1,
    unsigned short* __restrict__ vT)
{
    __shared__ unsigned short As[128][72];
    const int r0 = blockIdx.x * 128, h = blockIdx.y;
    const int t = threadIdx.x;
    const int wave = t >> 6, lane = t & 63;
    const int lrow = lane & 15, lgrp = lane >> 4;

    #pragma unroll
    for (int i = 0; i < 4; ++i) {
        int c = t + i * 256, rr = c >> 3, off = (c & 7) * 8;
        *(us8*)&As[rr][off] = *(const us8*)(mid + (size_t)(r0 + rr) * HDIM + h*64 + off);
    }
    __syncthreads();
    bf16x8 af[2][2];
    #pragma unroll
    for (int m = 0; m < 2; ++m)
        #pragma unroll
        for (int kf = 0; kf < 2; ++kf)
            af[m][kf] = ldb(&As[wave*32 + m*16 + lrow][kf*32 + lgrp*8]);

    const unsigned short* ws[3] = {wq, wk, wv};
    const float* bs[3] = {bq, bk, bv};
    unsigned short* ds[2] = {q1, k1};
    #pragma unroll
    for (int o = 0; o < 3; ++o) {
        bf16x8 bfr[4][2];
        #pragma unroll
        for (int n = 0; n < 4; ++n)
            #pragma unroll
            for (int kf = 0; kf < 2; ++kf)
                bfr[n][kf] = __builtin_bit_cast(bf16x8,
                    *(const us8*)(ws[o] + (size_t)(n*16 + lrow) * 64 + kf*32 + lgrp*8));
        f32x4 acc[2][4];
        #pragma unroll
        for (int m = 0; m < 2; ++m)
            #pragma unroll
            for (int n = 0; n < 4; ++n) {
                f32x4 z = (f32x4){0.f, 0.f, 0.f, 0.f};
                z = mfma_bf16(af[m][0], bfr[n][0], z);
                z = mfma_bf16(af[m][1], bfr[n][1], z);
                acc[m][n] = z;
            }
        #pragma unroll
        for (int m = 0; m < 2; ++m)
            #pragma unroll
            for (int n = 0; n < 4; ++n) {
                float bb = bs[o][n*16 + lrow];
                if (o < 2) {
                    #pragma unroll
                    for (int q = 0; q < 4; ++q) {
                        int gr = r0 + wave*32 + m*16 + lgrp*4 + q;
                        int bi = gr / MIDL, sq = gr % MIDL;
                        size_t drow = (size_t)bi * TOT + 64 + sq;
                        ds[o][drow * HDIM + h*64 + n*16 + lrow] = f2bf(acc[m][n][q] + bb);
                    }
                } else {
                    int gr = r0 + wave*32 + m*16 + lgrp*4;   // 4-aligned, MIDL%4==0
                    int bi = gr / MIDL, sq = gr % MIDL;
                    u32x2 w;
                    w[0] = cvt_pk_bf16(acc[m][n][0] + bb, acc[m][n][1] + bb);
                    w[1] = cvt_pk_bf16(acc[m][n][2] + bb, acc[m][n][3] + bb);
                    *(u32x2*)(vT + ((size_t)(bi*NHEAD + h)*64 + (n*16+lrow))*TOT
                              + 64 + sq) = w;
                }
            }
    }
}

// Task rows: q1<-q0.task, k1<-k0.task (row copies); vT seq[0,64) <- q0.task
// TRANSPOSED (reference quirk: kv = q0 task slice).
__global__ __launch_bounds__(256) void k_copy_task(
    const unsigned short* __restrict__ q0, const unsigned short* __restrict__ k0,
    unsigned short* __restrict__ q1, unsigned short* __restrict__ k1,
    unsigned short* __restrict__ vT)
{
    int blk = blockIdx.x;
    int t = threadIdx.x;
    if (blk < 256) {
        int tensor = blk >> 7, rem = blk & 127;
        int b = rem >> 6, rr = rem & 63;
        const unsigned short* src = tensor ? k0 : q0;
        unsigned short* dst = tensor ? k1 : q1;
        size_t srow = (size_t)b * TOT + MIDL + rr;
        size_t drow = (size_t)b * TOT + rr;
        if (t < 128)
            ((us8*)(dst + drow * HDIM))[t] = ((const us8*)(src + srow * HDIM))[t];
    } else {
        int rem = blk - 256;                  // 32 blocks: b(2) x h(16)
        int b = rem >> 4, h = rem & 15;
        const unsigned short* src = q0 + ((size_t)b * TOT + MIDL) * HDIM + h * 64;
        unsigned short* dst = vT + ((size_t)(b*NHEAD + h) * 64) * TOT;
        #pragma unroll
        for (int i = 0; i < 16; ++i) {
            int idx = t + i * 256;            // 4096 elems: r=idx&63, d=idx>>6
            int r = idx & 63, d = idx >> 6;
            dst[(size_t)d * TOT + r] = src[(size_t)r * HDIM + d];
        }
    }
}

// ---------------------------------------------------------------- launcher
extern "C" void kernel_launch(void* const* d_in, const int* in_sizes, int n_in,
                              void* d_out, int out_size, void* d_ws, size_t ws_size,
                              hipStream_t stream)
{
    (void)in_sizes; (void)n_in; (void)out_size; (void)ws_size;
    const float* vis = (const float*)d_in[0];
    const float* txt = (const float*)d_in[1];
    const float* tsk = (const float*)d_in[2];
    const float* wq0 = (const float*)d_in[3];
    const float* bq0 = (const float*)d_in[4];
    const float* wk0 = (const float*)d_in[5];
    const float* bk0 = (const float*)d_in[6];
    const float* wv0 = (const float*)d_in[7];
    const float* bv0 = (const float*)d_in[8];
    const float* wq1 = (const float*)d_in[9];
    const float* bq1 = (const float*)d_in[10];
    const float* wk1 = (const float*)d_in[11];
    const float* bk1 = (const float*)d_in[12];
    const float* wv1 = (const float*)d_in[13];
    const float* bv1 = (const float*)d_in[14];
    const float* wo  = (const float*)d_in[15];
    const float* bo  = (const float*)d_in[16];

    char* ws = (char*)d_ws;
    size_t off = 0;
    auto carve = [&](size_t bytes) -> char* {
        char* p = ws + off;
        off += (bytes + 255) & ~(size_t)255;
        return p;
    };
    const size_t ELX = (size_t)NB * TOT * HDIM;
    unsigned short* X     = (unsigned short*)carve(ELX * 2);
    unsigned short* q0    = (unsigned short*)carve(ELX * 2);
    unsigned short* k0    = (unsigned short*)carve(ELX * 2);
    unsigned short* vT    = (unsigned short*)carve(ELX * 2);  // [b][h][d][seq]
    unsigned short* wqkvb = (unsigned short*)carve((size_t)3 * HDIM * HDIM * 2);
    unsigned short* wob   = (unsigned short*)carve((size_t)HDIM * HDIM * 2);
    unsigned short* wq1b  = (unsigned short*)carve(64 * 64 * 2);
    unsigned short* wk1b  = (unsigned short*)carve(64 * 64 * 2);
    unsigned short* wv1b  = (unsigned short*)carve(64 * 64 * 2);
    unsigned short* mid   = X;     // X dead after QKV GEMM
    unsigned short* q1    = q0;    // in-place stage-2 tensors
    unsigned short* k1    = k0;
    unsigned short* out2  = X;     // mid dead after midlin

    // softmax in exp2 domain: scale = (1/64) * log2(e)
    const float scale = 1.44269504088896341f / 64.0f;

    k_cast_hs<<<5120, 256, 0, stream>>>(vis, txt, tsk, X);
    k_cast<<<1024, 256, 0, stream>>>(wq0, wqkvb,                 HDIM * HDIM);
    k_cast<<<1024, 256, 0, stream>>>(wk0, wqkvb + 1024*1024,     HDIM * HDIM);
    k_cast<<<1024, 256, 0, stream>>>(wv0, wqkvb + 2*1024*1024,   HDIM * HDIM);
    k_cast<<<1024, 256, 0, stream>>>(wo,  wob,  HDIM * HDIM);
    k_cast<<<4, 256, 0, stream>>>(wq1, wq1b, 64 * 64);
    k_cast<<<4, 256, 0, stream>>>(wk1, wk1b, 64 * 64);
    k_cast<<<4, 256, 0, stream>>>(wv1, wv1b, 64 * 64);

    // Fused QKV projection (v plane transposed)
    k_gemm_qkv<<<dim3(40, 24), 256, 0, stream>>>(
        X, wqkvb, bq0, bk0, bv0, q0, k0, vT);

    // v2t: Q=vision, K=text rows, V=text seqs -> mid rows [0,2048)
    k_attn<<<dim3(VL/64, NHEAD, NB), 256, 0, stream>>>(
        q0, k0 + (size_t)VL * HDIM, vT, mid,
        TL, (size_t)TOT * HDIM, (size_t)TOT * HDIM, VL, (size_t)MIDL * HDIM, scale);
    // t2v: Q=text, K=vision rows, V=vision seqs -> mid rows [2048,2496)
    k_attn<<<dim3(TL/64, NHEAD, NB), 256, 0, stream>>>(
        q0 + (size_t)VL * HDIM, k0, vT, mid + (size_t)VL * HDIM,
        VL, (size_t)TOT * HDIM, (size_t)TOT * HDIM, 0, (size_t)MIDL * HDIM, scale);

    // task rows (reads q0/k0 task before midlin overwrites), then mid linear
    k_copy_task<<<288, 256, 0, stream>>>(q0, k0, q1, k1, vT);
    k_midlin<<<dim3(39, NHEAD), 256, 0, stream>>>(
        mid, wq1b, wk1b, wv1b, bq1, bk1, bv1, q1, k1, vT);

    // stage-2 attention over [task, v2t, t2v]
    k_attn<<<dim3(TOT/64, NHEAD, NB), 256, 0, stream>>>(
        q1, k1, vT, out2,
        TOT, (size_t)TOT * HDIM, (size_t)TOT * HDIM, 0, (size_t)TOT * HDIM, scale);

    k_gemm_bt<false><<<dim3(40, 8), 256, 0, stream>>>(out2, wob, bo, (float*)d_out,
                                                      NB*TOT, HDIM, HDIM);
}

// Round 8
// 381.185 us; speedup vs baseline: 1.6694x; 1.0219x over previous
//
#include <hip/hip_runtime.h>
#include <math.h>

// Problem constants
#define NB   2
#define VL   2048
#define TL   448
#define KL   64
#define TOT  2560     // VL+TL+KL
#define MIDL 2496     // VL+TL
#define HDIM 1024
#define NHEAD 16
#define DHEAD 64

typedef __bf16 bf16x8 __attribute__((ext_vector_type(8)));
typedef float  f32x4  __attribute__((ext_vector_type(4)));
typedef unsigned short us8 __attribute__((ext_vector_type(8)));
typedef float  fl4    __attribute__((ext_vector_type(4)));
typedef unsigned int u32x2 __attribute__((ext_vector_type(2)));

__device__ __forceinline__ unsigned short f2bf(float f) {
    unsigned int u = __builtin_bit_cast(unsigned int, f);
    u += 0x7FFFu + ((u >> 16) & 1u);           // RNE
    return (unsigned short)(u >> 16);
}
__device__ __forceinline__ f32x4 mfma_bf16(bf16x8 a, bf16x8 b, f32x4 c) {
    return __builtin_amdgcn_mfma_f32_16x16x32_bf16(a, b, c, 0, 0, 0);
}
__device__ __forceinline__ bf16x8 ldb(const unsigned short* p) {
    return __builtin_bit_cast(bf16x8, *(const us8*)p);
}
// packed f32x2 -> bf16x2 (RNE), T12 recipe
__device__ __forceinline__ unsigned cvt_pk_bf16(float lo, float hi) {
    unsigned r;
    asm("v_cvt_pk_bf16_f32 %0, %1, %2" : "=v"(r) : "v"(lo), "v"(hi));
    return r;
}
__device__ __forceinline__ float exp2_fast(float x) {   // 2^x, raw v_exp
    float r;
    asm("v_exp_f32 %0, %1" : "=v"(r) : "v"(x));
    return r;
}

// ---------------------------------------------------------------- casts
__global__ __launch_bounds__(256) void k_cast_hs(
    const float* __restrict__ vis, const float* __restrict__ txt,
    const float* __restrict__ tsk, unsigned short* __restrict__ X)
{
    size_t idx = ((size_t)blockIdx.x * 256 + threadIdx.x) * 4;
    if (idx >= (size_t)NB * TOT * HDIM) return;
    size_t r = idx >> 10; int c = (int)(idx & 1023);
    int b = (int)(r / TOT), s = (int)(r % TOT);
    const float* src;
    if (s < VL)        src = vis + ((size_t)b * VL + s) * HDIM;
    else if (s < MIDL) src = txt + ((size_t)b * TL + (s - VL)) * HDIM;
    else               src = tsk + ((size_t)b * KL + (s - MIDL)) * HDIM;
    fl4 v = *(const fl4*)(src + c);
    X[idx + 0] = f2bf(v[0]); X[idx + 1] = f2bf(v[1]);
    X[idx + 2] = f2bf(v[2]); X[idx + 3] = f2bf(v[3]);
}

__global__ __launch_bounds__(256) void k_cast(
    const float* __restrict__ in, unsigned short* __restrict__ out, int n)
{
    int idx = (blockIdx.x * 256 + threadIdx.x) * 4;
    if (idx >= n) return;
    fl4 v = *(const fl4*)(in + idx);
    out[idx + 0] = f2bf(v[0]); out[idx + 1] = f2bf(v[1]);
    out[idx + 2] = f2bf(v[2]); out[idx + 3] = f2bf(v[3]);
}

// ---------------------------------------------------------------- GEMM (out-proj)
template<bool BF16OUT>
__global__ __launch_bounds__(256) void k_gemm_bt(
    const unsigned short* __restrict__ A, const unsigned short* __restrict__ W,
    const float* __restrict__ bias, void* __restrict__ Cv,
    int M, int N, int K)
{
    __shared__ unsigned short As[128][40];
    __shared__ unsigned short Bs[128][40];
    const int row0 = blockIdx.x * 128, col0 = blockIdx.y * 128;
    const int t = threadIdx.x;
    const int lane = t & 63, wave = t >> 6;
    const int wr = wave >> 1, wc = wave & 1;
    const int lrow = lane & 15, lgrp = lane >> 4;

    f32x4 acc[4][4];
    #pragma unroll
    for (int m = 0; m < 4; ++m)
        #pragma unroll
        for (int n = 0; n < 4; ++n)
            acc[m][n] = (f32x4){0.f, 0.f, 0.f, 0.f};

    const int r = t >> 1, hc = (t & 1) * 16;
    const unsigned short* Ap = A + (size_t)(row0 + r) * K + hc;
    const unsigned short* Wp = W + (size_t)(col0 + r) * K + hc;

    for (int kk = 0; kk < K; kk += 32) {
        us8 a0 = *(const us8*)(Ap + kk);
        us8 a1 = *(const us8*)(Ap + kk + 8);
        us8 b0 = *(const us8*)(Wp + kk);
        us8 b1 = *(const us8*)(Wp + kk + 8);
        __syncthreads();
        *(us8*)&As[r][hc]     = a0;
        *(us8*)&As[r][hc + 8] = a1;
        *(us8*)&Bs[r][hc]     = b0;
        *(us8*)&Bs[r][hc + 8] = b1;
        __syncthreads();
        bf16x8 af[4], bfr[4];
        #pragma unroll
        for (int m = 0; m < 4; ++m) af[m]  = ldb(&As[wr*64 + m*16 + lrow][lgrp*8]);
        #pragma unroll
        for (int n = 0; n < 4; ++n) bfr[n] = ldb(&Bs[wc*64 + n*16 + lrow][lgrp*8]);
        #pragma unroll
        for (int m = 0; m < 4; ++m)
            #pragma unroll
            for (int n = 0; n < 4; ++n)
                acc[m][n] = mfma_bf16(af[m], bfr[n], acc[m][n]);
    }
    #pragma unroll
    for (int m = 0; m < 4; ++m) {
        #pragma unroll
        for (int n = 0; n < 4; ++n) {
            int col = col0 + wc*64 + n*16 + lrow;
            float bs = bias[col];
            #pragma unroll
            for (int q = 0; q < 4; ++q) {
                int row = row0 + wr*64 + m*16 + lgrp*4 + q;
                float v = acc[m][n][q] + bs;
                if (BF16OUT) ((unsigned short*)Cv)[(size_t)row * N + col] = f2bf(v);
                else         ((float*)Cv)[(size_t)row * N + col] = v;
            }
        }
    }
}

// Fused QKV: M=5120, N=3072 (planes q|k|v), K=1024. q/k row-major;
// v written TRANSPOSED per head: vT[(b*NHEAD+h)*64 + d][seq] (8B stores).
__global__ __launch_bounds__(256) void k_gemm_qkv(
    const unsigned short* __restrict__ A, const unsigned short* __restrict__ W,
    const float* __restrict__ b0, const float* __restrict__ b1,
    const float* __restrict__ b2,
    unsigned short* __restrict__ C0, unsigned short* __restrict__ C1,
    unsigned short* __restrict__ vT)
{
    __shared__ unsigned short As[128][40];
    __shared__ unsigned short Bs[128][40];
    const int row0 = blockIdx.x * 128, col0 = blockIdx.y * 128;
    const int t = threadIdx.x;
    const int lane = t & 63, wave = t >> 6;
    const int wr = wave >> 1, wc = wave & 1;
    const int lrow = lane & 15, lgrp = lane >> 4;

    f32x4 acc[4][4];
    #pragma unroll
    for (int m = 0; m < 4; ++m)
        #pragma unroll
        for (int n = 0; n < 4; ++n)
            acc[m][n] = (f32x4){0.f, 0.f, 0.f, 0.f};

    const int r = t >> 1, hc = (t & 1) * 16;
    const unsigned short* Ap = A + (size_t)(row0 + r) * HDIM + hc;
    const unsigned short* Wp = W + (size_t)(col0 + r) * HDIM + hc;

    for (int kk = 0; kk < HDIM; kk += 32) {
        us8 a0 = *(const us8*)(Ap + kk);
        us8 a1 = *(const us8*)(Ap + kk + 8);
        us8 b0v = *(const us8*)(Wp + kk);
        us8 b1v = *(const us8*)(Wp + kk + 8);
        __syncthreads();
        *(us8*)&As[r][hc]     = a0;
        *(us8*)&As[r][hc + 8] = a1;
        *(us8*)&Bs[r][hc]     = b0v;
        *(us8*)&Bs[r][hc + 8] = b1v;
        __syncthreads();
        bf16x8 af[4], bfr[4];
        #pragma unroll
        for (int m = 0; m < 4; ++m) af[m]  = ldb(&As[wr*64 + m*16 + lrow][lgrp*8]);
        #pragma unroll
        for (int n = 0; n < 4; ++n) bfr[n] = ldb(&Bs[wc*64 + n*16 + lrow][lgrp*8]);
        #pragma unroll
        for (int m = 0; m < 4; ++m)
            #pragma unroll
            for (int n = 0; n < 4; ++n)
                acc[m][n] = mfma_bf16(af[m], bfr[n], acc[m][n]);
    }
    const int plane = col0 >> 10;
    const int cl0 = col0 & 1023;
    if (plane < 2) {
        const float* bp = (plane == 0) ? b0 : b1;
        unsigned short* Cp = (plane == 0) ? C0 : C1;
        #pragma unroll
        for (int m = 0; m < 4; ++m)
            #pragma unroll
            for (int n = 0; n < 4; ++n) {
                int col = cl0 + wc*64 + n*16 + lrow;
                float bs = bp[col];
                #pragma unroll
                for (int q = 0; q < 4; ++q) {
                    int row = row0 + wr*64 + m*16 + lgrp*4 + q;
                    Cp[(size_t)row * HDIM + col] = f2bf(acc[m][n][q] + bs);
                }
            }
    } else {
        // v plane: transposed store. 4 accum elems = 4 consecutive seq.
        #pragma unroll
        for (int m = 0; m < 4; ++m)
            #pragma unroll
            for (int n = 0; n < 4; ++n) {
                int col = cl0 + wc*64 + n*16 + lrow;
                int hh = col >> 6, dd = col & 63;
                float bs = b2[col];
                int rowb = row0 + wr*64 + m*16 + lgrp*4;   // 4-aligned, no b-cross
                int bb = rowb / TOT, sq = rowb % TOT;
                u32x2 w;
                w[0] = cvt_pk_bf16(acc[m][n][0] + bs, acc[m][n][1] + bs);
                w[1] = cvt_pk_bf16(acc[m][n][2] + bs, acc[m][n][3] + bs);
                *(u32x2*)(vT + ((size_t)(bb*NHEAD + hh)*64 + dd)*TOT + sq) = w;
            }
    }
}

// ---------------------------------------------------------------- attention
// Flash-style, grid (Lq/64, NHEAD, NB), 128 threads = 2 waves x 32 q-rows.
// Register-blocked q: each kf/v frag read feeds 2 MFMAs (two q-halves qh).
// Raw-score softmax: exponent = fmaf(s, sc, -sc*m) (scale folded into exp2
// arg, sc = log2e/64). T13 defer-max: skip rescale while mt-mr <= 8/sc.
// V PRE-TRANSPOSED in HBM; T14 prefetch of next K/V tile.
__global__ __launch_bounds__(128, 3) void k_attn(
    const unsigned short* __restrict__ Qb, const unsigned short* __restrict__ Kb,
    const unsigned short* __restrict__ vT, unsigned short* __restrict__ Ob,
    int Lk, size_t q_bs, size_t k_bs, int v_seq0, size_t o_bs, float sc)
{
    __shared__ unsigned short QV[64 * 72];     // Qs[64][72], then Vs[64 d][72]
    __shared__ unsigned short Ks[64][72];
    __shared__ unsigned short Pl[2][32][72];   // per-wave P[q 0..31][key]

    const int b = blockIdx.z, h = blockIdx.y, qb = blockIdx.x;
    const unsigned short* Q = Qb + (size_t)b * q_bs + h * 64;
    const unsigned short* K = Kb + (size_t)b * k_bs + h * 64;
    const unsigned short* V = vT + ((size_t)(b*NHEAD + h) * 64) * TOT + v_seq0;
    unsigned short*       O = Ob + (size_t)b * o_bs + h * 64;
    const int t = threadIdx.x;
    const int w = t >> 6, lane = t & 63;
    const int lrow = lane & 15, lgrp = lane >> 4;
    const int q0r = qb * 64;

    // stage Q tile [64][64]: 128 thr x 4 iters x us8
    const int srow = t >> 3, soff = (t & 7) * 8;   // row base 0..15, col 0..56
    #pragma unroll
    for (int i = 0; i < 4; ++i)
        *(us8*)&QV[(srow + i*16)*72 + soff] =
            *(const us8*)(Q + (size_t)(q0r + srow + i*16) * HDIM + soff);
    __syncthreads();
    bf16x8 qf[2][2];
    #pragma unroll
    for (int qh = 0; qh < 2; ++qh) {
        qf[qh][0] = ldb(&QV[(w*32 + qh*16 + lrow)*72 + lgrp*8]);
        qf[qh][1] = ldb(&QV[(w*32 + qh*16 + lrow)*72 + 32 + lgrp*8]);
    }
    // QV reused as Vs after the first in-loop barrier (qf reads drained there).

    f32x4 oacc[2][4];          // oacc[qh][df][r] = O[q=w*32+qh*16+lrow][df*16+lgrp*4+r]
    #pragma unroll
    for (int qh = 0; qh < 2; ++qh)
        #pragma unroll
        for (int d = 0; d < 4; ++d) oacc[qh][d] = (f32x4){0.f, 0.f, 0.f, 0.f};
    float mr0 = -INFINITY, mr1 = -INFINITY;    // raw-domain running max
    float ls0 = 0.f, ls1 = 0.f;
    float msc0 = 0.f, msc1 = 0.f;              // sc*mr (valid once finite)
    const float THRR = 8.0f / sc;

    const unsigned short* Kp = K + (size_t)srow * HDIM + soff;
    const unsigned short* Vp = V + (size_t)srow * TOT + soff;

    const int nkt = Lk >> 6;
    us8 ka[4], va[4];
    #pragma unroll
    for (int i = 0; i < 4; ++i) {
        ka[i] = *(const us8*)(Kp + (size_t)(i*16) * HDIM);
        va[i] = *(const us8*)(Vp + (size_t)(i*16) * TOT);
    }

    for (int kt = 0; kt < nkt; ++kt) {
        __syncthreads();                       // prior tile reads (and qf) done
        #pragma unroll
        for (int i = 0; i < 4; ++i) {
            *(us8*)&Ks[srow + i*16][soff] = ka[i];
            *(us8*)&QV[(srow + i*16)*72 + soff] = va[i];
        }
        if (kt + 1 < nkt) {                    // T14: prefetch before compute
            #pragma unroll
            for (int i = 0; i < 4; ++i) {
                ka[i] = *(const us8*)(Kp + (size_t)((kt+1)*64 + i*16) * HDIM);
                va[i] = *(const us8*)(Vp + (size_t)(i*16) * TOT + (kt+1)*64);
            }
        }
        __syncthreads();

        // S^T raw: s[nf][qh][reg] = S[key=nf*16+lgrp*4+reg][q=w*32+qh*16+lrow]
        f32x4 s[4][2];
        #pragma unroll
        for (int nf = 0; nf < 4; ++nf) {
            bf16x8 kf0 = ldb(&Ks[nf*16 + lrow][lgrp*8]);
            bf16x8 kf1 = ldb(&Ks[nf*16 + lrow][32 + lgrp*8]);
            #pragma unroll
            for (int qh = 0; qh < 2; ++qh) {
                f32x4 z = (f32x4){0.f, 0.f, 0.f, 0.f};
                z = mfma_bf16(kf0, qf[qh][0], z);
                z = mfma_bf16(kf1, qf[qh][1], z);
                s[nf][qh] = z;
            }
        }
        // online softmax, raw domain, per lane 2 rows
        float mt0 = s[0][0][0], mt1 = s[0][1][0];
        #pragma unroll
        for (int nf = 0; nf < 4; ++nf)
            #pragma unroll
            for (int rg = 0; rg < 4; ++rg) {
                mt0 = fmaxf(mt0, s[nf][0][rg]);
                mt1 = fmaxf(mt1, s[nf][1][rg]);
            }
        mt0 = fmaxf(mt0, __shfl_xor(mt0, 16)); mt0 = fmaxf(mt0, __shfl_xor(mt0, 32));
        mt1 = fmaxf(mt1, __shfl_xor(mt1, 16)); mt1 = fmaxf(mt1, __shfl_xor(mt1, 32));
        if (!__all((mt0 - mr0 <= THRR) && (mt1 - mr1 <= THRR))) {
            float n0 = fmaxf(mr0, mt0), n1 = fmaxf(mr1, mt1);
            float a0 = exp2_fast(sc * (mr0 - n0));
            float a1 = exp2_fast(sc * (mr1 - n1));
            mr0 = n0; mr1 = n1; msc0 = sc * n0; msc1 = sc * n1;
            ls0 *= a0; ls1 *= a1;
            #pragma unroll
            for (int d = 0; d < 4; ++d) { oacc[0][d] *= a0; oacc[1][d] *= a1; }
        }

        float rs0 = 0.f, rs1 = 0.f;
        #pragma unroll
        for (int nf = 0; nf < 4; ++nf) {
            float p00 = exp2_fast(fmaf(s[nf][0][0], sc, -msc0));
            float p01 = exp2_fast(fmaf(s[nf][0][1], sc, -msc0));
            float p02 = exp2_fast(fmaf(s[nf][0][2], sc, -msc0));
            float p03 = exp2_fast(fmaf(s[nf][0][3], sc, -msc0));
            rs0 += (p00 + p01) + (p02 + p03);
            u32x2 w0;
            w0[0] = cvt_pk_bf16(p00, p01);
            w0[1] = cvt_pk_bf16(p02, p03);
            *(u32x2*)&Pl[w][lrow][nf*16 + lgrp*4] = w0;
            float p10 = exp2_fast(fmaf(s[nf][1][0], sc, -msc1));
            float p11 = exp2_fast(fmaf(s[nf][1][1], sc, -msc1));
            float p12 = exp2_fast(fmaf(s[nf][1][2], sc, -msc1));
            float p13 = exp2_fast(fmaf(s[nf][1][3], sc, -msc1));
            rs1 += (p10 + p11) + (p12 + p13);
            u32x2 w1;
            w1[0] = cvt_pk_bf16(p10, p11);
            w1[1] = cvt_pk_bf16(p12, p13);
            *(u32x2*)&Pl[w][16 + lrow][nf*16 + lgrp*4] = w1;
        }
        rs0 += __shfl_xor(rs0, 16); rs0 += __shfl_xor(rs0, 32);
        rs1 += __shfl_xor(rs1, 16); rs1 += __shfl_xor(rs1, 32);
        ls0 += rs0; ls1 += rs1;

        // PV (O^T form): A = V^T frags (shared), B = P frags per qh
        bf16x8 pb[2][2];
        #pragma unroll
        for (int qh = 0; qh < 2; ++qh) {
            pb[qh][0] = ldb(&Pl[w][qh*16 + lrow][lgrp*8]);
            pb[qh][1] = ldb(&Pl[w][qh*16 + lrow][32 + lgrp*8]);
        }
        #pragma unroll
        for (int df = 0; df < 4; ++df) {
            int d = df*16 + lrow;
            bf16x8 v0 = ldb(&QV[d*72 + lgrp*8]);          // V^T[d][k=8lgrp+j]
            bf16x8 v1 = ldb(&QV[d*72 + 32 + lgrp*8]);     // k=32+8lgrp+j
            #pragma unroll
            for (int qh = 0; qh < 2; ++qh) {
                oacc[qh][df] = mfma_bf16(v0, pb[qh][0], oacc[qh][df]);
                oacc[qh][df] = mfma_bf16(v1, pb[qh][1], oacc[qh][df]);
            }
        }
    }
    const float rcp0 = 1.0f / ls0, rcp1 = 1.0f / ls1;
    #pragma unroll
    for (int qh = 0; qh < 2; ++qh) {
        const float rcp = qh ? rcp1 : rcp0;
        const int row = q0r + w*32 + qh*16 + lrow;
        #pragma unroll
        for (int df = 0; df < 4; ++df) {
            u32x2 wv;
            wv[0] = cvt_pk_bf16(oacc[qh][df][0] * rcp, oacc[qh][df][1] * rcp);
            wv[1] = cvt_pk_bf16(oacc[qh][df][2] * rcp, oacc[qh][df][3] * rcp);
            *(u32x2*)(O + (size_t)row * HDIM + df*16 + lgrp*4) = wv;
        }
    }
}

// ---------------------------------------------------------------- mid linear
// q1/k1 row-major in place; v1 written transposed into vT (seq offset +64).
__global__ __launch_bounds__(256) void k_midlin(
    const unsigned short* __restrict__ mid,
    const unsigned short* __restrict__ wq, const unsigned short* __restrict__ wk,
    const unsigned short* __restrict__ wv,
    const float* __restrict__ bq, const float* __restrict__ bk,
    const float* __restrict__ bv,
    unsigned short* __restrict__ q1, unsigned short* __restrict__ k1,
    unsigned short* __restrict__ vT)
{
    __shared__ unsigned short As[128][72];
    const int r0 = blockIdx.x * 128, h = blockIdx.y;
    const int t = threadIdx.x;
    const int wave = t >> 6, lane = t & 63;
    const int lrow = lane & 15, lgrp = lane >> 4;

    #pragma unroll
    for (int i = 0; i < 4; ++i) {
        int c = t + i * 256, rr = c >> 3, off = (c & 7) * 8;
        *(us8*)&As[rr][off] = *(const us8*)(mid + (size_t)(r0 + rr) * HDIM + h*64 + off);
    }
    __syncthreads();
    bf16x8 af[2][2];
    #pragma unroll
    for (int m = 0; m < 2; ++m)
        #pragma unroll
        for (int kf = 0; kf < 2; ++kf)
            af[m][kf] = ldb(&As[wave*32 + m*16 + lrow][kf*32 + lgrp*8]);

    const unsigned short* ws[3] = {wq, wk, wv};
    const float* bs[3] = {bq, bk, bv};
    unsigned short* ds[2] = {q1, k1};
    #pragma unroll
    for (int o = 0; o < 3; ++o) {
        bf16x8 bfr[4][2];
        #pragma unroll
        for (int n = 0; n < 4; ++n)
            #pragma unroll
            for (int kf = 0; kf < 2; ++kf)
                bfr[n][kf] = __builtin_bit_cast(bf16x8,
                    *(const us8*)(ws[o] + (size_t)(n*16 + lrow) * 64 + kf*32 + lgrp*8));
        f32x4 acc[2][4];
        #pragma unroll
        for (int m = 0; m < 2; ++m)
            #pragma unroll
            for (int n = 0; n < 4; ++n) {
                f32x4 z = (f32x4){0.f, 0.f, 0.f, 0.f};
                z = mfma_bf16(af[m][0], bfr[n][0], z);
                z = mfma_bf16(af[m][1], bfr[n][1], z);
                acc[m][n] = z;
            }
        #pragma unroll
        for (int m = 0; m < 2; ++m)
            #pragma unroll
            for (int n = 0; n < 4; ++n) {
                float bb = bs[o][n*16 + lrow];
                if (o < 2) {
                    #pragma unroll
                    for (int q = 0; q < 4; ++q) {
                        int gr = r0 + wave*32 + m*16 + lgrp*4 + q;
                        int bi = gr / MIDL, sq = gr % MIDL;
                        size_t drow = (size_t)bi * TOT + 64 + sq;
                        ds[o][drow * HDIM + h*64 + n*16 + lrow] = f2bf(acc[m][n][q] + bb);
                    }
                } else {
                    int gr = r0 + wave*32 + m*16 + lgrp*4;   // 4-aligned, MIDL%4==0
                    int bi = gr / MIDL, sq = gr % MIDL;
                    u32x2 w;
                    w[0] = cvt_pk_bf16(acc[m][n][0] + bb, acc[m][n][1] + bb);
                    w[1] = cvt_pk_bf16(acc[m][n][2] + bb, acc[m][n][3] + bb);
                    *(u32x2*)(vT + ((size_t)(bi*NHEAD + h)*64 + (n*16+lrow))*TOT
                              + 64 + sq) = w;
                }
            }
    }
}

// Task rows: q1<-q0.task, k1<-k0.task (row copies); vT seq[0,64) <- q0.task
// TRANSPOSED (reference quirk: kv = q0 task slice).
__global__ __launch_bounds__(256) void k_copy_task(
    const unsigned short* __restrict__ q0, const unsigned short* __restrict__ k0,
    unsigned short* __restrict__ q1, unsigned short* __restrict__ k1,
    unsigned short* __restrict__ vT)
{
    int blk = blockIdx.x;
    int t = threadIdx.x;
    if (blk < 256) {
        int tensor = blk >> 7, rem = blk & 127;
        int b = rem >> 6, rr = rem & 63;
        const unsigned short* src = tensor ? k0 : q0;
        unsigned short* dst = tensor ? k1 : q1;
        size_t srow = (size_t)b * TOT + MIDL + rr;
        size_t drow = (size_t)b * TOT + rr;
        if (t < 128)
            ((us8*)(dst + drow * HDIM))[t] = ((const us8*)(src + srow * HDIM))[t];
    } else {
        int rem = blk - 256;                  // 32 blocks: b(2) x h(16)
        int b = rem >> 4, h = rem & 15;
        const unsigned short* src = q0 + ((size_t)b * TOT + MIDL) * HDIM + h * 64;
        unsigned short* dst = vT + ((size_t)(b*NHEAD + h) * 64) * TOT;
        #pragma unroll
        for (int i = 0; i < 16; ++i) {
            int idx = t + i * 256;            // 4096 elems: r=idx&63, d=idx>>6
            int r = idx & 63, d = idx >> 6;
            dst[(size_t)d * TOT + r] = src[(size_t)r * HDIM + d];
        }
    }
}

// ---------------------------------------------------------------- launcher
extern "C" void kernel_launch(void* const* d_in, const int* in_sizes, int n_in,
                              void* d_out, int out_size, void* d_ws, size_t ws_size,
                              hipStream_t stream)
{
    (void)in_sizes; (void)n_in; (void)out_size; (void)ws_size;
    const float* vis = (const float*)d_in[0];
    const float* txt = (const float*)d_in[1];
    const float* tsk = (const float*)d_in[2];
    const float* wq0 = (const float*)d_in[3];
    const float* bq0 = (const float*)d_in[4];
    const float* wk0 = (const float*)d_in[5];
    const float* bk0 = (const float*)d_in[6];
    const float* wv0 = (const float*)d_in[7];
    const float* bv0 = (const float*)d_in[8];
    const float* wq1 = (const float*)d_in[9];
    const float* bq1 = (const float*)d_in[10];
    const float* wk1 = (const float*)d_in[11];
    const float* bk1 = (const float*)d_in[12];
    const float* wv1 = (const float*)d_in[13];
    const float* bv1 = (const float*)d_in[14];
    const float* wo  = (const float*)d_in[15];
    const float* bo  = (const float*)d_in[16];

    char* ws = (char*)d_ws;
    size_t off = 0;
    auto carve = [&](size_t bytes) -> char* {
        char* p = ws + off;
        off += (bytes + 255) & ~(size_t)255;
        return p;
    };
    const size_t ELX = (size_t)NB * TOT * HDIM;
    unsigned short* X     = (unsigned short*)carve(ELX * 2);
    unsigned short* q0    = (unsigned short*)carve(ELX * 2);
    unsigned short* k0    = (unsigned short*)carve(ELX * 2);
    unsigned short* vT    = (unsigned short*)carve(ELX * 2);  // [b][h][d][seq]
    unsigned short* wqkvb = (unsigned short*)carve((size_t)3 * HDIM * HDIM * 2);
    unsigned short* wob   = (unsigned short*)carve((size_t)HDIM * HDIM * 2);
    unsigned short* wq1b  = (unsigned short*)carve(64 * 64 * 2);
    unsigned short* wk1b  = (unsigned short*)carve(64 * 64 * 2);
    unsigned short* wv1b  = (unsigned short*)carve(64 * 64 * 2);
    unsigned short* mid   = X;     // X dead after QKV GEMM
    unsigned short* q1    = q0;    // in-place stage-2 tensors
    unsigned short* k1    = k0;
    unsigned short* out2  = X;     // mid dead after midlin

    // raw-score softmax: exponent scale = (1/64) * log2(e)
    const float sc = 1.44269504088896341f / 64.0f;

    k_cast_hs<<<5120, 256, 0, stream>>>(vis, txt, tsk, X);
    k_cast<<<1024, 256, 0, stream>>>(wq0, wqkvb,                 HDIM * HDIM);
    k_cast<<<1024, 256, 0, stream>>>(wk0, wqkvb + 1024*1024,     HDIM * HDIM);
    k_cast<<<1024, 256, 0, stream>>>(wv0, wqkvb + 2*1024*1024,   HDIM * HDIM);
    k_cast<<<1024, 256, 0, stream>>>(wo,  wob,  HDIM * HDIM);
    k_cast<<<4, 256, 0, stream>>>(wq1, wq1b, 64 * 64);
    k_cast<<<4, 256, 0, stream>>>(wk1, wk1b, 64 * 64);
    k_cast<<<4, 256, 0, stream>>>(wv1, wv1b, 64 * 64);

    // Fused QKV projection (v plane transposed)
    k_gemm_qkv<<<dim3(40, 24), 256, 0, stream>>>(
        X, wqkvb, bq0, bk0, bv0, q0, k0, vT);

    // v2t: Q=vision, K=text rows, V=text seqs -> mid rows [0,2048)
    k_attn<<<dim3(VL/64, NHEAD, NB), 128, 0, stream>>>(
        q0, k0 + (size_t)VL * HDIM, vT, mid,
        TL, (size_t)TOT * HDIM, (size_t)TOT * HDIM, VL, (size_t)MIDL * HDIM, sc);
    // t2v: Q=text, K=vision rows, V=vision seqs -> mid rows [2048,2496)
    k_attn<<<dim3(TL/64, NHEAD, NB), 128, 0, stream>>>(
        q0 + (size_t)VL * HDIM, k0, vT, mid + (size_t)VL * HDIM,
        VL, (size_t)TOT * HDIM, (size_t)TOT * HDIM, 0, (size_t)MIDL * HDIM, sc);

    // task rows (reads q0/k0 task before midlin overwrites), then mid linear
    k_copy_task<<<288, 256, 0, stream>>>(q0, k0, q1, k1, vT);
    k_midlin<<<dim3(39, NHEAD), 256, 0, stream>>>(
        mid, wq1b, wk1b, wv1b, bq1, bk1, bv1, q1, k1, vT);

    // stage-2 attention over [task, v2t, t2v]
    k_attn<<<dim3(TOT/64, NHEAD, NB), 128, 0, stream>>>(
        q1, k1, vT, out2,
        TOT, (size_t)TOT * HDIM, (size_t)TOT * HDIM, 0, (size_t)TOT * HDIM, sc);

    k_gemm_bt<false><<<dim3(40, 8), 256, 0, stream>>>(out2, wob, bo, (float*)d_out,
                                                      NB*TOT, HDIM, HDIM);
}